// Round 2
// baseline (857.203 us; speedup 1.0000x reference)
//
#include <hip/hip_runtime.h>

typedef unsigned int u32;
typedef unsigned short u16;
typedef unsigned long long u64;

#define LN_EPS 1e-5f
#define ATTN_EPS 1e-6f

typedef __bf16 bf16x8 __attribute__((ext_vector_type(8)));
typedef short shortx8 __attribute__((ext_vector_type(8)));
typedef float fx4 __attribute__((ext_vector_type(4)));

__device__ __forceinline__ u16 f2bf(float f){
  union{float f; u32 u;} x; x.f = f;
  u32 r = 0x7fffu + ((x.u>>16)&1u);
  return (u16)((x.u + r)>>16);
}
__device__ __forceinline__ float bf2f(u16 u){
  union{u32 u; float f;} x; x.u = ((u32)u)<<16; return x.f;
}
__device__ __forceinline__ bf16x8 ldfrag(const u16* p){
  return __builtin_bit_cast(bf16x8, *(const shortx8*)p);
}

// ---------- async global->LDS 16B ----------
__device__ __forceinline__ void async16(const void* g, void* l){
  typedef const __attribute__((address_space(1))) void gas_t;
  typedef __attribute__((address_space(3))) void las_t;
  __builtin_amdgcn_global_load_lds((gas_t*)(u64)g, (las_t*)(u32)(u64)l, 16, 0, 0);
}

// ---------- dtype detect ----------
__global__ void detect_kernel(const u16* __restrict__ ln1g, int* __restrict__ flag){
  if (threadIdx.x == 0 && blockIdx.x == 0)
    *flag = (ln1g[0] == 0x3F80u) ? 1 : 0;
}

// ---------- all small params in one launch ----------
__global__ __launch_bounds__(256) void cvt_small(
    const void* p0, const void* p1, const void* p2, const void* p3,
    const void* p4, const void* p5, const void* p6, const void* p7,
    const void* p8, const void* p9, const void* p10,
    float* __restrict__ out, const int* __restrict__ flagp)
{
  int i = blockIdx.x*256 + threadIdx.x;
  if (i >= 46080) return;
  const void* src; int off;
  if      (i < 3072)  { src=p0;  off=i; }
  else if (i < 6144)  { src=p1;  off=i-3072; }
  else if (i < 9216)  { src=p2;  off=i-6144; }
  else if (i < 12288) { src=p3;  off=i-9216; }
  else if (i < 18432) { src=p4;  off=i-12288; }
  else if (i < 21504) { src=p5;  off=i-18432; }
  else if (i < 24576) { src=p6;  off=i-21504; }
  else if (i < 27648) { src=p7;  off=i-24576; }
  else if (i < 30720) { src=p8;  off=i-27648; }
  else if (i < 43008) { src=p9;  off=i-30720; }
  else                { src=p10; off=i-43008; }
  float v;
  if (*flagp){ union{u32 u; float f;} x; x.u = ((u32)((const u16*)src)[off])<<16; v = x.f; }
  else v = ((const float*)src)[off];
  out[i] = v;
}

// ---------- x convert: f32 + bf16 mirror ----------
__global__ __launch_bounds__(256) void cvt_x(const void* __restrict__ in, float* __restrict__ out,
                                             u16* __restrict__ outbf, int n, const int* __restrict__ flagp){
  int i = blockIdx.x*256 + threadIdx.x;
  if (i >= n) return;
  float v;
  if (*flagp){ union{u32 u; float f;} x; x.u = ((u32)((const u16*)in)[i])<<16; v = x.f; }
  else v = ((const float*)in)[i];
  out[i] = v;
  outbf[i] = f2bf(v);
}

// ---------- weight transpose + convert with layer z: W[K,N] -> Wt[N,K] bf16 ----------
__global__ __launch_bounds__(256) void transpose_cvtL(
    const void* __restrict__ W, u16* __restrict__ Wt,
    int K, int N, size_t zsrc, size_t zdst, const int* __restrict__ flagp)
{
  __shared__ float s[32][33];
  const size_t eoff = (size_t)blockIdx.z * zsrc;
  Wt += (size_t)blockIdx.z * zdst;
  const int bx = blockIdx.x, by = blockIdx.y;
  const int tid = threadIdx.x;
  const int c = tid & 31, r = tid >> 5;
  const int isbf = *flagp;
#pragma unroll
  for (int i = 0; i < 4; ++i){
    int k = by*32 + r + i*8, n = bx*32 + c;
    size_t idx = eoff + (size_t)k*N + n;
    float v;
    if (isbf){ union{u32 u; float f;} x; x.u = ((u32)((const u16*)W)[idx])<<16; v = x.f; }
    else v = ((const float*)W)[idx];
    s[r + i*8][c] = v;
  }
  __syncthreads();
#pragma unroll
  for (int i = 0; i < 4; ++i){
    int n = bx*32 + r + i*8, k = by*32 + c;
    Wt[(size_t)n*K + k] = f2bf(s[c][r + i*8]);
  }
}

// ---------- all 12 QKVO square transposes (3 layers x 4 mats) ----------
__global__ __launch_bounds__(256) void transpose_cvtQ(
    const void* __restrict__ W0, const void* __restrict__ W1,
    const void* __restrict__ W2, const void* __restrict__ W3,
    u16* __restrict__ Wt, const int* __restrict__ flagp)
{
  __shared__ float s[32][33];
  const int z = blockIdx.z, l = z >> 2, m = z & 3;
  const void* W = (m==0)?W0:((m==1)?W1:((m==2)?W2:W3));
  const size_t eoff = (size_t)l * 1048576;
  Wt += (size_t)z * 1048576;
  const int bx = blockIdx.x, by = blockIdx.y;
  const int tid = threadIdx.x;
  const int c = tid & 31, r = tid >> 5;
  const int isbf = *flagp;
#pragma unroll
  for (int i = 0; i < 4; ++i){
    int k = by*32 + r + i*8, n = bx*32 + c;
    size_t idx = eoff + (size_t)k*1024 + n;
    float v;
    if (isbf){ union{u32 u; float f;} x; x.u = ((u32)((const u16*)W)[idx])<<16; v = x.f; }
    else v = ((const float*)W)[idx];
    s[r + i*8][c] = v;
  }
  __syncthreads();
#pragma unroll
  for (int i = 0; i < 4; ++i){
    int n = bx*32 + r + i*8, k = by*32 + c;
    Wt[(size_t)n*1024 + k] = f2bf(s[c][r + i*8]);
  }
}

// ---------- 3-stage pipelined MFMA GEMM, 128x64 tile, BK=32, 256 threads ----------
// R8: smaller tile -> 3-4 independent blocks (barrier domains) per CU so blocks
// stall out-of-phase (m102/m114: block-level overlap is what hides the per-iter
// vmcnt+barrier drain; 8 waves in ONE block lockstep and don't). 36KB LDS,
// 3 loads/stage/thread -> vmcnt(3) cadence. XCD 2D-chunk swizzle kept.
__global__ __launch_bounds__(256, 1) void mfma_gemm(
    const u16* __restrict__ A, const u16* __restrict__ W,
    const float* __restrict__ bias,
    float* __restrict__ C, u16* __restrict__ Cbf,
    int N, int Kst, int kstep_z, int klen,
    size_t wz, size_t cz, int bz, int bias_all, int relu)
{
  __shared__ u16 As[3][128*32];
  __shared__ u16 Bs[3][64*32];
  const int z = blockIdx.z;
  W    += (size_t)z * wz;
  bias += (size_t)z * bz;
  if (C) C += (size_t)z * cz;
  const int kbeg = z * kstep_z;
  const int tid = threadIdx.x;
  const int lane = tid & 63, wid = tid >> 6;

  // ---- XCD-aware 2D chunk swizzle (8 XCDs as 4x2 grid of chunks) ----
  int bx = blockIdx.x, by = blockIdx.y;
  {
    const int gx = gridDim.x, gy = gridDim.y;
    if (((gx & 3) == 0) && ((gy & 1) == 0)) {
      const int cw = gx >> 2, ch = gy >> 1;     // chunk dims
      if (((cw & (cw-1)) == 0) && ((ch & (ch-1)) == 0)) {
        const int o = by*gx + bx;
        const int xcd = o & 7, k = o >> 3;
        const int lgw = 31 - __clz(cw);
        bx = (xcd & 3)*cw + (k & (cw-1));
        by = (xcd >> 2)*ch + (k >> lgw);
      }
    }
  }
  const int row0 = by * 128, col0 = bx * 64;

  const int ar = tid >> 2, ae = (tid & 3) << 3;   // 4 thr/row, 8 elems each
  const u16* gA0 = A + (size_t)(row0 + ar)*Kst + kbeg + ae;        // rows 0..63
  const u16* gA1 = A + (size_t)(row0 + 64 + ar)*Kst + kbeg + ae;   // rows 64..127
  const u16* gB0 = W + (size_t)(col0 + ar)*Kst + kbeg + ae;        // 64 rows

  const int iters = klen >> 5;
#pragma unroll
  for (int s = 0; s < 2; ++s){
    const int ko = s*32;
    async16(gA0 + ko, &As[s][tid*8]);
    async16(gA1 + ko, &As[s][2048 + tid*8]);
    async16(gB0 + ko, &Bs[s][tid*8]);
  }

  const int quad = lane >> 4, l16 = lane & 15;
  const int wr = (wid >> 1) * 64, wc = (wid & 1) * 32;   // 2x2 wave grid, 64x32 each
  fx4 acc[4][2] = {};

  for (int it = 0; it < iters; ++it){
    const int cur = it % 3;
    __builtin_amdgcn_s_waitcnt(0x0F73);   // vmcnt(3): stage it landed, it+1 in flight
    __builtin_amdgcn_s_barrier();
    {
      const int nx   = (it + 2 < iters) ? (it + 2) : (iters - 1);
      const int nbuf = (it + 2) % 3;
      const int ko = nx*32;
      async16(gA0 + ko, &As[nbuf][tid*8]);
      async16(gA1 + ko, &As[nbuf][2048 + tid*8]);
      async16(gB0 + ko, &Bs[nbuf][tid*8]);
    }
    bf16x8 af[4], bfr[2];
#pragma unroll
    for (int t = 0; t < 4; ++t)
      af[t] = ldfrag(&As[cur][(wr + t*16 + l16)*32 + quad*8]);
#pragma unroll
    for (int u = 0; u < 2; ++u)
      bfr[u] = ldfrag(&Bs[cur][(wc + u*16 + l16)*32 + quad*8]);
#pragma unroll
    for (int t = 0; t < 4; ++t)
#pragma unroll
      for (int u = 0; u < 2; ++u)
        acc[t][u] = __builtin_amdgcn_mfma_f32_16x16x32_bf16(af[t], bfr[u], acc[t][u], 0, 0, 0);
  }
  __builtin_amdgcn_s_waitcnt(0x0F70);     // vmcnt(0)

  const int r0 = quad * 4;
#pragma unroll
  for (int u = 0; u < 2; ++u){
    const int col = col0 + wc + u*16 + l16;
    const float bv = (bias_all || z == 0) ? bias[col] : 0.f;
#pragma unroll
    for (int t = 0; t < 4; ++t){
      const int rowb = row0 + wr + t*16 + r0;
#pragma unroll
      for (int r = 0; r < 4; ++r){
        float v = acc[t][u][r] + bv;
        if (relu) v = fmaxf(v, 0.f);
        if (C)   C[(size_t)(rowb + r)*N + col] = v;
        if (Cbf) Cbf[(size_t)(rowb + r)*N + col] = f2bf(v);
      }
    }
  }
}

// ---------- FAVOR feature map; K phi -> f32 (for chunk_kv) ; Q,K phi -> bf16 mirrors ----------
__global__ __launch_bounds__(256) void favor_kernel(
    float* __restrict__ Q, float* __restrict__ Kp, const float* __restrict__ omega,
    u16* __restrict__ Qb, u16* __restrict__ Kb)
{
  __shared__ float sh[4][64];
  __shared__ float sho[64][32];
  int tid = threadIdx.x;
  for (int i = tid; i < 2048; i += 256)
    sho[i>>5][i&31] = omega[i];
  int wv = tid >> 6, lane = tid & 63;
  int th = blockIdx.x*4 + wv;
  size_t base = (size_t)(th >> 4) * 1024 + (size_t)(th & 15) * 64;
  int jm = lane & 31;
  float sgn = (lane < 32) ? 1.f : -1.f;
  for (int w = 0; w < 2; ++w){
    float* p = w ? Kp : Q;
    float xs = p[base + lane] * 0.35355339059327373f;
    __syncthreads();
    sh[wv][lane] = xs;
    __syncthreads();
    float u = 0.f, hh = 0.f;
#pragma unroll
    for (int d = 0; d < 64; ++d){
      float xv = sh[wv][d];
      u  = fmaf(xv, sho[d][jm], u);
      hh = fmaf(xv, xv, hh);
    }
    float phi = expf(sgn*u - 0.5f*hh) * 0.125f;
    if (w) p[base + lane] = phi;                 // K f32 kept for chunk_kv/Ksum
    (w ? Kb : Qb)[base + lane] = f2bf(phi);      // bf16 mirrors for MFMA attn
  }
}

// ---------- per-chunk KVt[d][m] = sum_j V[j][d] K[j][m], Ksum = sum_j k_j ----------
__global__ __launch_bounds__(256) void chunk_kv(
    const float* __restrict__ Kf, const float* __restrict__ V,
    float* __restrict__ KV, float* __restrict__ Ksum)
{
  __shared__ float Ks[64][64];
  __shared__ float Vs[64][64];
  int blk = blockIdx.x;
  int c = blk & 15, h = (blk >> 4) & 15, b = blk >> 8;
  int tid = threadIdx.x;
  for (int i = tid; i < 1024; i += 256){
    int j = i >> 4, m4 = (i & 15) << 2;
    size_t src = ((size_t)(b*1024 + c*64 + j)*16 + h)*64 + m4;
    *(float4*)&Ks[j][m4] = *(const float4*)&Kf[src];
    *(float4*)&Vs[j][m4] = *(const float4*)&V[src];
  }
  __syncthreads();
  int m = tid & 63, dg = tid >> 6;    // lane = m (coalesced KVt writes), wave-uniform d-group
  float acc[16] = {0.f};
  for (int j = 0; j < 64; ++j){
    float kv = Ks[j][m];
#pragma unroll
    for (int di = 0; di < 16; ++di)
      acc[di] = fmaf(Vs[j][dg*16+di], kv, acc[di]);
  }
  size_t outb = (size_t)blk * 4096;
#pragma unroll
  for (int di = 0; di < 16; ++di)
    KV[outb + (size_t)(dg*16+di)*64 + m] = acc[di];   // KVt[d][m]
  if (tid < 64){
    float s = 0.f;
    for (int j = 0; j < 64; ++j) s += Ks[j][tid];
    Ksum[(size_t)blk*64 + tid] = s;
  }
}

// ---------- exclusive prefix over chunks (elementwise; layout-agnostic) ----------
__global__ __launch_bounds__(256) void chunk_scan(float* __restrict__ KV, float* __restrict__ Ksum)
{
  int blk = blockIdx.x;
  int bh = blk >> 4, ec = blk & 15;
  int e = ec*256 + threadIdx.x;
  size_t base = (size_t)bh * 65536 + e;
  float run = 0.f;
  for (int c = 0; c < 16; ++c){
    size_t idx = base + (size_t)c*4096;
    float t = KV[idx]; KV[idx] = run; run += t;
  }
  if (ec == 0 && threadIdx.x < 64){
    size_t kb = (size_t)bh * 1024 + threadIdx.x;
    float rz = 0.f;
    for (int c = 0; c < 16; ++c){
      size_t idx = kb + c*64;
      float t = Ksum[idx]; Ksum[idx] = rz; rz += t;
    }
  }
}

// ---------- MFMA intra-chunk causal attention ----------
__global__ __launch_bounds__(256) void attn_kernel(
    const u16* __restrict__ Qbf, const u16* __restrict__ Kbf,
    const float* __restrict__ V, const float* __restrict__ KVt,
    const float* __restrict__ Ksum, u16* __restrict__ Outbf)
{
  __shared__ u16 Qs[64][72];
  __shared__ u16 Ks[64][72];
  __shared__ u16 Ss[64][72];
  __shared__ u16 Vt[64][72];
  __shared__ u16 Pt[64][72];
  __shared__ float Vrow[64][68];
  __shared__ float densum[64];

  const int blk = blockIdx.x;
  const int c = blk & 15, h = (blk >> 4) & 15, b = blk >> 8;
  const int tid = threadIdx.x;
  const int lane = tid & 63, w = tid >> 6;
  const int quad = lane >> 4, l16 = lane & 15;
  const int t0 = b*1024 + c*64;

  {
    const int r = tid >> 2, q4 = (tid & 3) << 4;   // 16 elems per thread
    size_t g = (size_t)(t0 + r)*1024 + h*64 + q4;
    *(uint4*)&Qs[r][q4]   = *(const uint4*)(Qbf + g);
    *(uint4*)&Qs[r][q4+8] = *(const uint4*)(Qbf + g + 8);
    *(uint4*)&Ks[r][q4]   = *(const uint4*)(Kbf + g);
    *(uint4*)&Ks[r][q4+8] = *(const uint4*)(Kbf + g + 8);
    const float* vg = V + g;
    *(float4*)&Vrow[r][q4+0]  = *(const float4*)(vg+0);
    *(float4*)&Vrow[r][q4+4]  = *(const float4*)(vg+4);
    *(float4*)&Vrow[r][q4+8]  = *(const float4*)(vg+8);
    *(float4*)&Vrow[r][q4+12] = *(const float4*)(vg+12);
    const float* pg = KVt + (size_t)blk*4096 + r*64 + q4;   // row d=r
    u16 tmp[16];
#pragma unroll
    for (int j = 0; j < 16; ++j) tmp[j] = f2bf(pg[j]);
    *(uint4*)&Pt[r][q4]   = *(uint4*)&tmp[0];
    *(uint4*)&Pt[r][q4+8] = *(uint4*)&tmp[8];
  }
  __syncthreads();
  {
    const int d = tid >> 2, j16 = (tid & 3) << 4;
    u16 tmp[16];
#pragma unroll
    for (int j = 0; j < 16; ++j) tmp[j] = f2bf(Vrow[j16+j][d]);
    *(uint4*)&Vt[d][j16]   = *(uint4*)&tmp[0];
    *(uint4*)&Vt[d][j16+8] = *(uint4*)&tmp[8];
  }

  const int iw0 = w*16;
  bf16x8 aq0 = ldfrag(&Qs[iw0+l16][quad*8]);
  bf16x8 aq1 = ldfrag(&Qs[iw0+l16][32+quad*8]);
  fx4 sacc[4];
#pragma unroll
  for (int u = 0; u < 4; ++u){
    sacc[u] = (fx4){0.f,0.f,0.f,0.f};
    bf16x8 b0 = ldfrag(&Ks[u*16+l16][quad*8]);
    bf16x8 b1 = ldfrag(&Ks[u*16+l16][32+quad*8]);
    sacc[u] = __builtin_amdgcn_mfma_f32_16x16x32_bf16(aq0, b0, sacc[u], 0, 0, 0);
    sacc[u] = __builtin_amdgcn_mfma_f32_16x16x32_bf16(aq1, b1, sacc[u], 0, 0, 0);
  }
  float rs[4] = {0.f,0.f,0.f,0.f};
#pragma unroll
  for (int u = 0; u < 4; ++u){
    const int jl = u*16 + l16;
#pragma unroll
    for (int r = 0; r < 4; ++r){
      const int il = iw0 + quad*4 + r;
      float v = (jl <= il) ? sacc[u][r] : 0.f;
      rs[r] += v;
      Ss[il][jl] = f2bf(v);
    }
  }
#pragma unroll
  for (int off = 1; off < 16; off <<= 1){
#pragma unroll
    for (int r = 0; r < 4; ++r) rs[r] += __shfl_xor(rs[r], off);
  }
  if (l16 == 0){
#pragma unroll
    for (int r = 0; r < 4; ++r) densum[iw0 + quad*4 + r] = rs[r];
  }
  __syncthreads();

  {
    const int row = iw0 + l16;
    const float* zp = Ksum + (size_t)blk*64;
    float dp = 0.f;
#pragma unroll
    for (int m = 0; m < 16; ++m){
      const int mm = quad*16 + m;
      dp = fmaf(bf2f(Qs[row][mm]), zp[mm], dp);
    }
    dp += __shfl_xor(dp, 16);
    dp += __shfl_xor(dp, 32);
    if (quad == 0) densum[row] = densum[row] + dp + ATTN_EPS;
  }
  __syncthreads();

  bf16x8 as0 = ldfrag(&Ss[iw0+l16][quad*8]);
  bf16x8 as1 = ldfrag(&Ss[iw0+l16][32+quad*8]);
  fx4 oacc[4];
#pragma unroll
  for (int u = 0; u < 4; ++u){
    const int d0 = u*16;
    oacc[u] = (fx4){0.f,0.f,0.f,0.f};
    oacc[u] = __builtin_amdgcn_mfma_f32_16x16x32_bf16(as0, ldfrag(&Vt[d0+l16][quad*8]),    oacc[u], 0,0,0);
    oacc[u] = __builtin_amdgcn_mfma_f32_16x16x32_bf16(as1, ldfrag(&Vt[d0+l16][32+quad*8]), oacc[u], 0,0,0);
    oacc[u] = __builtin_amdgcn_mfma_f32_16x16x32_bf16(aq0, ldfrag(&Pt[d0+l16][quad*8]),    oacc[u], 0,0,0);
    oacc[u] = __builtin_amdgcn_mfma_f32_16x16x32_bf16(aq1, ldfrag(&Pt[d0+l16][32+quad*8]), oacc[u], 0,0,0);
  }
#pragma unroll
  for (int u = 0; u < 4; ++u){
    const int d = u*16 + l16;
#pragma unroll
    for (int r = 0; r < 4; ++r){
      const int il = iw0 + quad*4 + r;
      const float o = oacc[u][r] / densum[il];
      Outbf[(size_t)(t0 + il)*1024 + h*64 + d] = f2bf(o);
    }
  }
}

// ---------- residual + LayerNorm: ln(X + Y0 + Y1 [+ Y2 + Y3]) ----------
__global__ __launch_bounds__(256) void resid_ln(
    const float* __restrict__ X, const float* __restrict__ Y0, const float* __restrict__ Y1,
    const float* __restrict__ Y2, const float* __restrict__ Y3,
    const float* __restrict__ g, const float* __restrict__ b,
    float* __restrict__ Dst, u16* __restrict__ DstBf,
    void* __restrict__ OutPtr, const int* __restrict__ flagp)
{
  __shared__ float rs[4], rss[4];
  int row = blockIdx.x, tid = threadIdx.x;
  int lane = tid & 63, wv = tid >> 6;
  size_t base = (size_t)row * 1024;
  int c = tid << 2;
  float4 xv = *(const float4*)&X[base + c];
  float4 y0 = *(const float4*)&Y0[base + c];
  float4 y1 = *(const float4*)&Y1[base + c];
  float v0 = xv.x+y0.x+y1.x, v1 = xv.y+y0.y+y1.y, v2 = xv.z+y0.z+y1.z, v3 = xv.w+y0.w+y1.w;
  if (Y2){
    float4 y2 = *(const float4*)&Y2[base + c];
    float4 y3 = *(const float4*)&Y3[base + c];
    v0 += y2.x + y3.x; v1 += y2.y + y3.y; v2 += y2.z + y3.z; v3 += y2.w + y3.w;
  }
  float s = v0+v1+v2+v3;
  float ss = v0*v0+v1*v1+v2*v2+v3*v3;
  for (int off = 32; off; off >>= 1){
    s  += __shfl_down(s, off);
    ss += __shfl_down(ss, off);
  }
  if (lane == 0){ rs[wv] = s; rss[wv] = ss; }
  __syncthreads();
  float S  = rs[0]+rs[1]+rs[2]+rs[3];
  float SS = rss[0]+rss[1]+rss[2]+rss[3];
  float mu = S * (1.f/1024.f);
  float var = SS * (1.f/1024.f) - mu*mu;
  float rinv = rsqrtf(var + LN_EPS);
  float4 gv = *(const float4*)(g + c);
  float4 bb = *(const float4*)(b + c);
  float o0 = (v0-mu)*rinv*gv.x + bb.x;
  float o1 = (v1-mu)*rinv*gv.y + bb.y;
  float o2 = (v2-mu)*rinv*gv.z + bb.z;
  float o3 = (v3-mu)*rinv*gv.w + bb.w;
  *(float4*)&Dst[base + c] = make_float4(o0,o1,o2,o3);
  uint2 ob;
  ob.x = (u32)f2bf(o0) | ((u32)f2bf(o1) << 16);
  ob.y = (u32)f2bf(o2) | ((u32)f2bf(o3) << 16);
  *(uint2*)(DstBf + base + c) = ob;
  if (OutPtr){
    if (*flagp){
      *(uint2*)((u16*)OutPtr + base + c) = ob;
    } else {
      *(float4*)((float*)OutPtr + base + c) = make_float4(o0,o1,o2,o3);
    }
  }
}

extern "C" void kernel_launch(void* const* d_in, const int* in_sizes, int n_in,
                              void* d_out, int out_size, void* d_ws, size_t ws_size,
                              hipStream_t stream)
{
  (void)in_sizes; (void)n_in; (void)out_size; (void)ws_size;

  float* ws   = (float*)d_ws;
  float* R    = ws;                    // 2M f32: x residual / layer input
  float* P0   = R  + 2097152;          // 4x2M contiguous: QKV out, split-K partials
  float* P1   = P0 + 2097152;
  float* P2   = P1 + 2097152;          // v f32
  float* P3   = P2 + 2097152;
  float* KVb  = P3 + 2097152;          // 2M: chunk states, then h (post-LN1) f32
  float* Ks   = KVb + 2097152;         // 32K chunk z
  float* smallP = Ks + 32768;          // 46080 f32 small params
  float* pend = smallP + 46080;
  int* flag = (int*)pend;
  u16* abf  = (u16*)(pend + 4);        // 2M: x / layer-out bf16
  u16* hbf  = abf  + 2097152;          // 2M: post-LN1 bf16
  u16* t1bf = hbf  + 2097152;          // 2M: attn out bf16
  u16* fbf  = t1bf + 2097152;          // 8M: ffn hidden bf16
  u16* qpbf = fbf  + 8388608;          // 2M: Q-phi bf16
  u16* kpbf = qpbf + 2097152;          // 2M: K-phi bf16
  u16* WtQ  = kpbf + 2097152;          // 12M: QKVO transposed, all layers
  u16* WtF1 = WtQ  + 12582912;         // 12M: FFN1 transposed, all layers
  u16* WtF2 = WtF1 + 12582912;         // 12M: FFN2 transposed, all layers

  float* bqF  = smallP + 0;
  float* boF  = smallP + 9216;
  float* omF  = smallP + 12288;
  float* l1gF = smallP + 18432;
  float* l1bF = smallP + 21504;
  float* l2gF = smallP + 24576;
  float* l2bF = smallP + 27648;
  float* bf1F = smallP + 30720;
  float* bf2F = smallP + 43008;

  detect_kernel<<<1, 64, 0, stream>>>((const u16*)d_in[10], flag);
  cvt_small<<<180, 256, 0, stream>>>(d_in[2], d_in[4], d_in[6], d_in[8], d_in[9],
                                     d_in[10], d_in[11], d_in[12], d_in[13],
                                     d_in[15], d_in[17], smallP, flag);
  cvt_x<<<8192, 256, 0, stream>>>(d_in[0], R, abf, 2097152, flag);

  // all weight transposes hoisted out of the layer loop
  transpose_cvtQ<<<dim3(32, 32, 12), 256, 0, stream>>>(d_in[1], d_in[3], d_in[5], d_in[7],
                                                       WtQ, flag);
  transpose_cvtL<<<dim3(128, 32, 3), 256, 0, stream>>>(d_in[14], WtF1, 1024, 4096,
                                                       4194304, 4194304, flag);
  transpose_cvtL<<<dim3(32, 128, 3), 256, 0, stream>>>(d_in[16], WtF2, 4096, 1024,
                                                       4194304, 4194304, flag);

  dim3 gQKV(16, 16, 3);   // 768 blocks, 3/CU
  dim3 gO(16, 16, 2);     // 512 blocks
  dim3 gF1(64, 16, 1);    // 1024 blocks, 4/CU
  dim3 gF2(16, 16, 4);    // 1024 blocks, 4/CU (split-K z=4)

  for (int l = 0; l < 3; ++l){
    const size_t wQ = (size_t)l * 4194304;

    mfma_gemm<<<gQKV, 256, 0, stream>>>(abf, WtQ + wQ, bqF + l*1024, P0, (u16*)nullptr,
                                        1024, 1024, 0, 1024,
                                        1048576, 2097152, 3072, 1, 0);
    favor_kernel<<<8192, 256, 0, stream>>>(P0, P1, omF + l*2048, qpbf, kpbf);
    chunk_kv<<<512, 256, 0, stream>>>(P1, P2, KVb, Ks);
    chunk_scan<<<512, 256, 0, stream>>>(KVb, Ks);
    attn_kernel<<<512, 256, 0, stream>>>(qpbf, kpbf, P2, KVb, Ks, t1bf);

    mfma_gemm<<<gO, 256, 0, stream>>>(t1bf, WtQ + wQ + 3145728, boF + l*1024, P0, (u16*)nullptr,
                                      1024, 1024, 512, 512,
                                      0, 2097152, 0, 0, 0);
    resid_ln<<<2048, 256, 0, stream>>>(R, P0, P1, nullptr, nullptr,
                                       l1gF + l*1024, l1bF + l*1024,
                                       KVb, hbf, nullptr, flag);

    mfma_gemm<<<gF1, 256, 0, stream>>>(hbf, WtF1 + wQ, bf1F + l*4096, (float*)nullptr, fbf,
                                       4096, 1024, 0, 1024,
                                       0, 0, 0, 1, 1);

    mfma_gemm<<<gF2, 256, 0, stream>>>(fbf, WtF2 + wQ, bf2F + l*1024, P0, (u16*)nullptr,
                                       1024, 4096, 1024, 1024,
                                       0, 2097152, 0, 0, 0);

    resid_ln<<<2048, 256, 0, stream>>>(KVb, P0, P1, P2, P3,
                                       l2gF + l*1024, l2bF + l*1024,
                                       R, abf, (l == 2) ? d_out : nullptr, flag);
  }
}

// Round 3
// 786.185 us; speedup vs baseline: 1.0903x; 1.0903x over previous
//
#include <hip/hip_runtime.h>

typedef unsigned int u32;
typedef unsigned short u16;
typedef unsigned long long u64;

#define LN_EPS 1e-5f
#define ATTN_EPS 1e-6f

typedef __bf16 bf16x8 __attribute__((ext_vector_type(8)));
typedef short shortx8 __attribute__((ext_vector_type(8)));
typedef float fx4 __attribute__((ext_vector_type(4)));
typedef float fx16 __attribute__((ext_vector_type(16)));

__device__ __forceinline__ u16 f2bf(float f){
  union{float f; u32 u;} x; x.f = f;
  u32 r = 0x7fffu + ((x.u>>16)&1u);
  return (u16)((x.u + r)>>16);
}
__device__ __forceinline__ float bf2f(u16 u){
  union{u32 u; float f;} x; x.u = ((u32)u)<<16; return x.f;
}
__device__ __forceinline__ bf16x8 ldfrag(const u16* p){
  return __builtin_bit_cast(bf16x8, *(const shortx8*)p);
}

// ---------- async global->LDS 16B ----------
__device__ __forceinline__ void async16(const void* g, void* l){
  typedef const __attribute__((address_space(1))) void gas_t;
  typedef __attribute__((address_space(3))) void las_t;
  __builtin_amdgcn_global_load_lds((gas_t*)(u64)g, (las_t*)(u32)(u64)l, 16, 0, 0);
}

// ---------- dtype detect ----------
__global__ void detect_kernel(const u16* __restrict__ ln1g, int* __restrict__ flag){
  if (threadIdx.x == 0 && blockIdx.x == 0)
    *flag = (ln1g[0] == 0x3F80u) ? 1 : 0;
}

// ---------- all small params in one launch ----------
__global__ __launch_bounds__(256) void cvt_small(
    const void* p0, const void* p1, const void* p2, const void* p3,
    const void* p4, const void* p5, const void* p6, const void* p7,
    const void* p8, const void* p9, const void* p10,
    float* __restrict__ out, const int* __restrict__ flagp)
{
  int i = blockIdx.x*256 + threadIdx.x;
  if (i >= 46080) return;
  const void* src; int off;
  if      (i < 3072)  { src=p0;  off=i; }
  else if (i < 6144)  { src=p1;  off=i-3072; }
  else if (i < 9216)  { src=p2;  off=i-6144; }
  else if (i < 12288) { src=p3;  off=i-9216; }
  else if (i < 18432) { src=p4;  off=i-12288; }
  else if (i < 21504) { src=p5;  off=i-18432; }
  else if (i < 24576) { src=p6;  off=i-21504; }
  else if (i < 27648) { src=p7;  off=i-24576; }
  else if (i < 30720) { src=p8;  off=i-27648; }
  else if (i < 43008) { src=p9;  off=i-30720; }
  else                { src=p10; off=i-43008; }
  float v;
  if (*flagp){ union{u32 u; float f;} x; x.u = ((u32)((const u16*)src)[off])<<16; v = x.f; }
  else v = ((const float*)src)[off];
  out[i] = v;
}

// ---------- x convert: f32 + bf16 mirror ----------
__global__ __launch_bounds__(256) void cvt_x(const void* __restrict__ in, float* __restrict__ out,
                                             u16* __restrict__ outbf, int n, const int* __restrict__ flagp){
  int i = blockIdx.x*256 + threadIdx.x;
  if (i >= n) return;
  float v;
  if (*flagp){ union{u32 u; float f;} x; x.u = ((u32)((const u16*)in)[i])<<16; v = x.f; }
  else v = ((const float*)in)[i];
  out[i] = v;
  outbf[i] = f2bf(v);
}

// ---------- weight transpose + convert with layer z: W[K,N] -> Wt[N,K] bf16 ----------
__global__ __launch_bounds__(256) void transpose_cvtL(
    const void* __restrict__ W, u16* __restrict__ Wt,
    int K, int N, size_t zsrc, size_t zdst, const int* __restrict__ flagp)
{
  __shared__ float s[32][33];
  const size_t eoff = (size_t)blockIdx.z * zsrc;
  Wt += (size_t)blockIdx.z * zdst;
  const int bx = blockIdx.x, by = blockIdx.y;
  const int tid = threadIdx.x;
  const int c = tid & 31, r = tid >> 5;
  const int isbf = *flagp;
#pragma unroll
  for (int i = 0; i < 4; ++i){
    int k = by*32 + r + i*8, n = bx*32 + c;
    size_t idx = eoff + (size_t)k*N + n;
    float v;
    if (isbf){ union{u32 u; float f;} x; x.u = ((u32)((const u16*)W)[idx])<<16; v = x.f; }
    else v = ((const float*)W)[idx];
    s[r + i*8][c] = v;
  }
  __syncthreads();
#pragma unroll
  for (int i = 0; i < 4; ++i){
    int n = bx*32 + r + i*8, k = by*32 + c;
    Wt[(size_t)n*K + k] = f2bf(s[c][r + i*8]);
  }
}

// ---------- all 12 QKVO square transposes (3 layers x 4 mats) ----------
__global__ __launch_bounds__(256) void transpose_cvtQ(
    const void* __restrict__ W0, const void* __restrict__ W1,
    const void* __restrict__ W2, const void* __restrict__ W3,
    u16* __restrict__ Wt, const int* __restrict__ flagp)
{
  __shared__ float s[32][33];
  const int z = blockIdx.z, l = z >> 2, m = z & 3;
  const void* W = (m==0)?W0:((m==1)?W1:((m==2)?W2:W3));
  const size_t eoff = (size_t)l * 1048576;
  Wt += (size_t)z * 1048576;
  const int bx = blockIdx.x, by = blockIdx.y;
  const int tid = threadIdx.x;
  const int c = tid & 31, r = tid >> 5;
  const int isbf = *flagp;
#pragma unroll
  for (int i = 0; i < 4; ++i){
    int k = by*32 + r + i*8, n = bx*32 + c;
    size_t idx = eoff + (size_t)k*1024 + n;
    float v;
    if (isbf){ union{u32 u; float f;} x; x.u = ((u32)((const u16*)W)[idx])<<16; v = x.f; }
    else v = ((const float*)W)[idx];
    s[r + i*8][c] = v;
  }
  __syncthreads();
#pragma unroll
  for (int i = 0; i < 4; ++i){
    int n = bx*32 + r + i*8, k = by*32 + c;
    Wt[(size_t)n*1024 + k] = f2bf(s[c][r + i*8]);
  }
}

// ---------- 3-stage pipelined MFMA GEMM, 128x128 tile, BK=32, 256 thr ----------
// R9: 32x32x16 MFMA, 4 waves each owning 64x64 (2x2 of 32x32, K split in 2).
// Same FLOP/block-iter as R7's 16x16 version but: LDS frag reads 48KB->32KB,
// ds_read 48->32, MFMA 64->32 at the higher 32x32 rate. LDS is kept LINEAR for
// global_load_lds (rule 21); bank conflicts on the 32-lane column reads are
// killed by an XOR-4 k-chunk swizzle applied on the GLOBAL source (staging) and
// the ds_read column (read): data kchunk c of row R lives at slot c^(R&3).
__global__ __launch_bounds__(256, 2) void mfma_gemm(
    const u16* __restrict__ A, const u16* __restrict__ W,
    const float* __restrict__ bias,
    float* __restrict__ C, u16* __restrict__ Cbf,
    int N, int Kst, int kstep_z, int klen,
    size_t wz, size_t cz, int bz, int bias_all, int relu)
{
  __shared__ u16 As[3][128*32];
  __shared__ u16 Bs[3][128*32];
  const int z = blockIdx.z;
  W    += (size_t)z * wz;
  bias += (size_t)z * bz;
  if (C) C += (size_t)z * cz;
  const int kbeg = z * kstep_z;
  const int tid = threadIdx.x;
  const int lane = tid & 63, wid = tid >> 6;

  // ---- XCD-aware 2D chunk swizzle (8 XCDs as 4x2 grid of chunks) ----
  int bx = blockIdx.x, by = blockIdx.y;
  {
    const int gx = gridDim.x, gy = gridDim.y;
    if (((gx & 3) == 0 || gx == 2 || gx == 8) && ((gy & 1) == 0)) {
      // use 4x2 chunking only when gx%4==0; for gx==8 it holds anyway
    }
    if (((gx & 3) == 0) && ((gy & 1) == 0)) {
      const int cw = gx >> 2, ch = gy >> 1;
      if (((cw & (cw-1)) == 0) && ((ch & (ch-1)) == 0)) {
        const int o = by*gx + bx;
        const int xcd = o & 7, k = o >> 3;
        const int lgw = 31 - __clz(cw);
        bx = (xcd & 3)*cw + (k & (cw-1));
        by = (xcd >> 2)*ch + (k >> lgw);
      }
    }
  }
  const int row0 = by * 128, col0 = bx * 128;

  // ---- staging: 4 waves x 2 instrs each cover 128 rows; LDS linear.
  // lane covers row 32*wid + 16*j + (lane>>2); its DATA k-chunk is
  // (lane&3)^((lane>>2)&3) == (lane&3)^(row&3)  -> lands at slot lane&3.
  const int sR = 32*wid + (lane >> 2);
  const int sC = (((lane & 3) ^ ((lane >> 2) & 3))) << 3;   // elems
  const u16* gA  = A + (size_t)(row0 + sR)*Kst + kbeg + sC;
  const u16* gAj = gA + (size_t)16 * Kst;
  const u16* gB  = W + (size_t)(col0 + sR)*Kst + kbeg + sC;
  const u16* gBj = gB + (size_t)16 * Kst;
  const int lb = wid*1024 + lane*8;   // LDS elem offset; +512 for j=1

  const int iters = klen >> 5;
#pragma unroll
  for (int s = 0; s < 2; ++s){
    const int ko = s*32;
    async16(gA  + ko, &As[s][lb]);
    async16(gAj + ko, &As[s][lb + 512]);
    async16(gB  + ko, &Bs[s][lb]);
    async16(gBj + ko, &Bs[s][lb + 512]);
  }

  const int l31 = lane & 31, hi = lane >> 5;
  const int wr = (wid >> 1) * 64, wc = (wid & 1) * 64;   // 2x2 wave grid, 64x64 each
  // swizzled read columns (elems): kchunk kh*2+hi lives at slot (kh*2+hi)^(row&3),
  // row&3 == lane&3 for all frag rows (wr, mt*32 are multiples of 4... of 32).
  const int rc0 = ((hi     ^ (lane & 3))) << 3;   // kh=0
  const int rc1 = (((2+hi) ^ (lane & 3))) << 3;   // kh=1
  fx16 acc[2][2] = {};

  for (int it = 0; it < iters; ++it){
    const int cur = it % 3;
    __builtin_amdgcn_s_waitcnt(0x0F74);   // vmcnt(4): stage it landed, it+1 in flight
    __builtin_amdgcn_s_barrier();
    {
      const int nx   = (it + 2 < iters) ? (it + 2) : (iters - 1);
      const int nbuf = (it + 2) % 3;
      const int ko = nx*32;
      async16(gA  + ko, &As[nbuf][lb]);
      async16(gAj + ko, &As[nbuf][lb + 512]);
      async16(gB  + ko, &Bs[nbuf][lb]);
      async16(gBj + ko, &Bs[nbuf][lb + 512]);
    }
    bf16x8 a0k0 = ldfrag(&As[cur][(wr      + l31)*32 + rc0]);
    bf16x8 a1k0 = ldfrag(&As[cur][(wr + 32 + l31)*32 + rc0]);
    bf16x8 b0k0 = ldfrag(&Bs[cur][(wc      + l31)*32 + rc0]);
    bf16x8 b1k0 = ldfrag(&Bs[cur][(wc + 32 + l31)*32 + rc0]);
    bf16x8 a0k1 = ldfrag(&As[cur][(wr      + l31)*32 + rc1]);
    bf16x8 a1k1 = ldfrag(&As[cur][(wr + 32 + l31)*32 + rc1]);
    bf16x8 b0k1 = ldfrag(&Bs[cur][(wc      + l31)*32 + rc1]);
    bf16x8 b1k1 = ldfrag(&Bs[cur][(wc + 32 + l31)*32 + rc1]);
    acc[0][0] = __builtin_amdgcn_mfma_f32_32x32x16_bf16(a0k0, b0k0, acc[0][0], 0,0,0);
    acc[0][1] = __builtin_amdgcn_mfma_f32_32x32x16_bf16(a0k0, b1k0, acc[0][1], 0,0,0);
    acc[1][0] = __builtin_amdgcn_mfma_f32_32x32x16_bf16(a1k0, b0k0, acc[1][0], 0,0,0);
    acc[1][1] = __builtin_amdgcn_mfma_f32_32x32x16_bf16(a1k0, b1k0, acc[1][1], 0,0,0);
    acc[0][0] = __builtin_amdgcn_mfma_f32_32x32x16_bf16(a0k1, b0k1, acc[0][0], 0,0,0);
    acc[0][1] = __builtin_amdgcn_mfma_f32_32x32x16_bf16(a0k1, b1k1, acc[0][1], 0,0,0);
    acc[1][0] = __builtin_amdgcn_mfma_f32_32x32x16_bf16(a1k1, b0k1, acc[1][0], 0,0,0);
    acc[1][1] = __builtin_amdgcn_mfma_f32_32x32x16_bf16(a1k1, b1k1, acc[1][1], 0,0,0);
  }
  __builtin_amdgcn_s_waitcnt(0x0F70);     // vmcnt(0)

  // C/D layout (32x32): col = lane&31, row = (r&3) + 8*(r>>2) + 4*(lane>>5)
  const int rbase = 4*hi;
#pragma unroll
  for (int nt = 0; nt < 2; ++nt){
    const int col = col0 + wc + nt*32 + l31;
    const float bv = (bias_all || z == 0) ? bias[col] : 0.f;
#pragma unroll
    for (int mt = 0; mt < 2; ++mt){
#pragma unroll
      for (int r = 0; r < 16; ++r){
        const int row = row0 + wr + mt*32 + rbase + (r & 3) + 8*(r >> 2);
        float v = acc[mt][nt][r] + bv;
        if (relu) v = fmaxf(v, 0.f);
        if (C)   C[(size_t)row*N + col] = v;
        if (Cbf) Cbf[(size_t)row*N + col] = f2bf(v);
      }
    }
  }
}

// ---------- FAVOR feature map; K phi -> f32 (for chunk_kv) ; Q,K phi -> bf16 mirrors ----------
__global__ __launch_bounds__(256) void favor_kernel(
    float* __restrict__ Q, float* __restrict__ Kp, const float* __restrict__ omega,
    u16* __restrict__ Qb, u16* __restrict__ Kb)
{
  __shared__ float sh[4][64];
  __shared__ float sho[64][32];
  int tid = threadIdx.x;
  for (int i = tid; i < 2048; i += 256)
    sho[i>>5][i&31] = omega[i];
  int wv = tid >> 6, lane = tid & 63;
  int th = blockIdx.x*4 + wv;
  size_t base = (size_t)(th >> 4) * 1024 + (size_t)(th & 15) * 64;
  int jm = lane & 31;
  float sgn = (lane < 32) ? 1.f : -1.f;
  for (int w = 0; w < 2; ++w){
    float* p = w ? Kp : Q;
    float xs = p[base + lane] * 0.35355339059327373f;
    __syncthreads();
    sh[wv][lane] = xs;
    __syncthreads();
    float u = 0.f, hh = 0.f;
#pragma unroll
    for (int d = 0; d < 64; ++d){
      float xv = sh[wv][d];
      u  = fmaf(xv, sho[d][jm], u);
      hh = fmaf(xv, xv, hh);
    }
    float phi = expf(sgn*u - 0.5f*hh) * 0.125f;
    if (w) p[base + lane] = phi;                 // K f32 kept for chunk_kv/Ksum
    (w ? Kb : Qb)[base + lane] = f2bf(phi);      // bf16 mirrors for MFMA attn
  }
}

// ---------- per-chunk KVt[d][m] = sum_j V[j][d] K[j][m], Ksum = sum_j k_j ----------
__global__ __launch_bounds__(256) void chunk_kv(
    const float* __restrict__ Kf, const float* __restrict__ V,
    float* __restrict__ KV, float* __restrict__ Ksum)
{
  __shared__ float Ks[64][64];
  __shared__ float Vs[64][64];
  int blk = blockIdx.x;
  int c = blk & 15, h = (blk >> 4) & 15, b = blk >> 8;
  int tid = threadIdx.x;
  for (int i = tid; i < 1024; i += 256){
    int j = i >> 4, m4 = (i & 15) << 2;
    size_t src = ((size_t)(b*1024 + c*64 + j)*16 + h)*64 + m4;
    *(float4*)&Ks[j][m4] = *(const float4*)&Kf[src];
    *(float4*)&Vs[j][m4] = *(const float4*)&V[src];
  }
  __syncthreads();
  int m = tid & 63, dg = tid >> 6;    // lane = m (coalesced KVt writes), wave-uniform d-group
  float acc[16] = {0.f};
  for (int j = 0; j < 64; ++j){
    float kv = Ks[j][m];
#pragma unroll
    for (int di = 0; di < 16; ++di)
      acc[di] = fmaf(Vs[j][dg*16+di], kv, acc[di]);
  }
  size_t outb = (size_t)blk * 4096;
#pragma unroll
  for (int di = 0; di < 16; ++di)
    KV[outb + (size_t)(dg*16+di)*64 + m] = acc[di];   // KVt[d][m]
  if (tid < 64){
    float s = 0.f;
    for (int j = 0; j < 64; ++j) s += Ks[j][tid];
    Ksum[(size_t)blk*64 + tid] = s;
  }
}

// ---------- exclusive prefix over chunks (elementwise; layout-agnostic) ----------
__global__ __launch_bounds__(256) void chunk_scan(float* __restrict__ KV, float* __restrict__ Ksum)
{
  int blk = blockIdx.x;
  int bh = blk >> 4, ec = blk & 15;
  int e = ec*256 + threadIdx.x;
  size_t base = (size_t)bh * 65536 + e;
  float run = 0.f;
  for (int c = 0; c < 16; ++c){
    size_t idx = base + (size_t)c*4096;
    float t = KV[idx]; KV[idx] = run; run += t;
  }
  if (ec == 0 && threadIdx.x < 64){
    size_t kb = (size_t)bh * 1024 + threadIdx.x;
    float rz = 0.f;
    for (int c = 0; c < 16; ++c){
      size_t idx = kb + c*64;
      float t = Ksum[idx]; Ksum[idx] = rz; rz += t;
    }
  }
}

// ---------- MFMA intra-chunk causal attention ----------
__global__ __launch_bounds__(256) void attn_kernel(
    const u16* __restrict__ Qbf, const u16* __restrict__ Kbf,
    const float* __restrict__ V, const float* __restrict__ KVt,
    const float* __restrict__ Ksum, u16* __restrict__ Outbf)
{
  __shared__ u16 Qs[64][72];
  __shared__ u16 Ks[64][72];
  __shared__ u16 Ss[64][72];
  __shared__ u16 Vt[64][72];
  __shared__ u16 Pt[64][72];
  __shared__ float Vrow[64][68];
  __shared__ float densum[64];

  const int blk = blockIdx.x;
  const int c = blk & 15, h = (blk >> 4) & 15, b = blk >> 8;
  const int tid = threadIdx.x;
  const int lane = tid & 63, w = tid >> 6;
  const int quad = lane >> 4, l16 = lane & 15;
  const int t0 = b*1024 + c*64;

  {
    const int r = tid >> 2, q4 = (tid & 3) << 4;   // 16 elems per thread
    size_t g = (size_t)(t0 + r)*1024 + h*64 + q4;
    *(uint4*)&Qs[r][q4]   = *(const uint4*)(Qbf + g);
    *(uint4*)&Qs[r][q4+8] = *(const uint4*)(Qbf + g + 8);
    *(uint4*)&Ks[r][q4]   = *(const uint4*)(Kbf + g);
    *(uint4*)&Ks[r][q4+8] = *(const uint4*)(Kbf + g + 8);
    const float* vg = V + g;
    *(float4*)&Vrow[r][q4+0]  = *(const float4*)(vg+0);
    *(float4*)&Vrow[r][q4+4]  = *(const float4*)(vg+4);
    *(float4*)&Vrow[r][q4+8]  = *(const float4*)(vg+8);
    *(float4*)&Vrow[r][q4+12] = *(const float4*)(vg+12);
    const float* pg = KVt + (size_t)blk*4096 + r*64 + q4;   // row d=r
    u16 tmp[16];
#pragma unroll
    for (int j = 0; j < 16; ++j) tmp[j] = f2bf(pg[j]);
    *(uint4*)&Pt[r][q4]   = *(uint4*)&tmp[0];
    *(uint4*)&Pt[r][q4+8] = *(uint4*)&tmp[8];
  }
  __syncthreads();
  {
    const int d = tid >> 2, j16 = (tid & 3) << 4;
    u16 tmp[16];
#pragma unroll
    for (int j = 0; j < 16; ++j) tmp[j] = f2bf(Vrow[j16+j][d]);
    *(uint4*)&Vt[d][j16]   = *(uint4*)&tmp[0];
    *(uint4*)&Vt[d][j16+8] = *(uint4*)&tmp[8];
  }

  const int iw0 = w*16;
  bf16x8 aq0 = ldfrag(&Qs[iw0+l16][quad*8]);
  bf16x8 aq1 = ldfrag(&Qs[iw0+l16][32+quad*8]);
  fx4 sacc[4];
#pragma unroll
  for (int u = 0; u < 4; ++u){
    sacc[u] = (fx4){0.f,0.f,0.f,0.f};
    bf16x8 b0 = ldfrag(&Ks[u*16+l16][quad*8]);
    bf16x8 b1 = ldfrag(&Ks[u*16+l16][32+quad*8]);
    sacc[u] = __builtin_amdgcn_mfma_f32_16x16x32_bf16(aq0, b0, sacc[u], 0, 0, 0);
    sacc[u] = __builtin_amdgcn_mfma_f32_16x16x32_bf16(aq1, b1, sacc[u], 0, 0, 0);
  }
  float rs[4] = {0.f,0.f,0.f,0.f};
#pragma unroll
  for (int u = 0; u < 4; ++u){
    const int jl = u*16 + l16;
#pragma unroll
    for (int r = 0; r < 4; ++r){
      const int il = iw0 + quad*4 + r;
      float v = (jl <= il) ? sacc[u][r] : 0.f;
      rs[r] += v;
      Ss[il][jl] = f2bf(v);
    }
  }
#pragma unroll
  for (int off = 1; off < 16; off <<= 1){
#pragma unroll
    for (int r = 0; r < 4; ++r) rs[r] += __shfl_xor(rs[r], off);
  }
  if (l16 == 0){
#pragma unroll
    for (int r = 0; r < 4; ++r) densum[iw0 + quad*4 + r] = rs[r];
  }
  __syncthreads();

  {
    const int row = iw0 + l16;
    const float* zp = Ksum + (size_t)blk*64;
    float dp = 0.f;
#pragma unroll
    for (int m = 0; m < 16; ++m){
      const int mm = quad*16 + m;
      dp = fmaf(bf2f(Qs[row][mm]), zp[mm], dp);
    }
    dp += __shfl_xor(dp, 16);
    dp += __shfl_xor(dp, 32);
    if (quad == 0) densum[row] = densum[row] + dp + ATTN_EPS;
  }
  __syncthreads();

  bf16x8 as0 = ldfrag(&Ss[iw0+l16][quad*8]);
  bf16x8 as1 = ldfrag(&Ss[iw0+l16][32+quad*8]);
  fx4 oacc[4];
#pragma unroll
  for (int u = 0; u < 4; ++u){
    const int d0 = u*16;
    oacc[u] = (fx4){0.f,0.f,0.f,0.f};
    oacc[u] = __builtin_amdgcn_mfma_f32_16x16x32_bf16(as0, ldfrag(&Vt[d0+l16][quad*8]),    oacc[u], 0,0,0);
    oacc[u] = __builtin_amdgcn_mfma_f32_16x16x32_bf16(as1, ldfrag(&Vt[d0+l16][32+quad*8]), oacc[u], 0,0,0);
    oacc[u] = __builtin_amdgcn_mfma_f32_16x16x32_bf16(aq0, ldfrag(&Pt[d0+l16][quad*8]),    oacc[u], 0,0,0);
    oacc[u] = __builtin_amdgcn_mfma_f32_16x16x32_bf16(aq1, ldfrag(&Pt[d0+l16][32+quad*8]), oacc[u], 0,0,0);
  }
#pragma unroll
  for (int u = 0; u < 4; ++u){
    const int d = u*16 + l16;
#pragma unroll
    for (int r = 0; r < 4; ++r){
      const int il = iw0 + quad*4 + r;
      const float o = oacc[u][r] / densum[il];
      Outbf[(size_t)(t0 + il)*1024 + h*64 + d] = f2bf(o);
    }
  }
}

// ---------- residual + LayerNorm: ln(X + Y0 + Y1 [+ Y2 + Y3]) ----------
__global__ __launch_bounds__(256) void resid_ln(
    const float* __restrict__ X, const float* __restrict__ Y0, const float* __restrict__ Y1,
    const float* __restrict__ Y2, const float* __restrict__ Y3,
    const float* __restrict__ g, const float* __restrict__ b,
    float* __restrict__ Dst, u16* __restrict__ DstBf,
    void* __restrict__ OutPtr, const int* __restrict__ flagp)
{
  __shared__ float rs[4], rss[4];
  int row = blockIdx.x, tid = threadIdx.x;
  int lane = tid & 63, wv = tid >> 6;
  size_t base = (size_t)row * 1024;
  int c = tid << 2;
  float4 xv = *(const float4*)&X[base + c];
  float4 y0 = *(const float4*)&Y0[base + c];
  float4 y1 = *(const float4*)&Y1[base + c];
  float v0 = xv.x+y0.x+y1.x, v1 = xv.y+y0.y+y1.y, v2 = xv.z+y0.z+y1.z, v3 = xv.w+y0.w+y1.w;
  if (Y2){
    float4 y2 = *(const float4*)&Y2[base + c];
    float4 y3 = *(const float4*)&Y3[base + c];
    v0 += y2.x + y3.x; v1 += y2.y + y3.y; v2 += y2.z + y3.z; v3 += y2.w + y3.w;
  }
  float s = v0+v1+v2+v3;
  float ss = v0*v0+v1*v1+v2*v2+v3*v3;
  for (int off = 32; off; off >>= 1){
    s  += __shfl_down(s, off);
    ss += __shfl_down(ss, off);
  }
  if (lane == 0){ rs[wv] = s; rss[wv] = ss; }
  __syncthreads();
  float S  = rs[0]+rs[1]+rs[2]+rs[3];
  float SS = rss[0]+rss[1]+rss[2]+rss[3];
  float mu = S * (1.f/1024.f);
  float var = SS * (1.f/1024.f) - mu*mu;
  float rinv = rsqrtf(var + LN_EPS);
  float4 gv = *(const float4*)(g + c);
  float4 bb = *(const float4*)(b + c);
  float o0 = (v0-mu)*rinv*gv.x + bb.x;
  float o1 = (v1-mu)*rinv*gv.y + bb.y;
  float o2 = (v2-mu)*rinv*gv.z + bb.z;
  float o3 = (v3-mu)*rinv*gv.w + bb.w;
  *(float4*)&Dst[base + c] = make_float4(o0,o1,o2,o3);
  uint2 ob;
  ob.x = (u32)f2bf(o0) | ((u32)f2bf(o1) << 16);
  ob.y = (u32)f2bf(o2) | ((u32)f2bf(o3) << 16);
  *(uint2*)(DstBf + base + c) = ob;
  if (OutPtr){
    if (*flagp){
      *(uint2*)((u16*)OutPtr + base + c) = ob;
    } else {
      *(float4*)((float*)OutPtr + base + c) = make_float4(o0,o1,o2,o3);
    }
  }
}

extern "C" void kernel_launch(void* const* d_in, const int* in_sizes, int n_in,
                              void* d_out, int out_size, void* d_ws, size_t ws_size,
                              hipStream_t stream)
{
  (void)in_sizes; (void)n_in; (void)out_size; (void)ws_size;

  float* ws   = (float*)d_ws;
  float* R    = ws;                    // 2M f32: x residual / layer input
  float* P0   = R  + 2097152;          // 4x2M contiguous: QKV out, split-K partials
  float* P1   = P0 + 2097152;
  float* P2   = P1 + 2097152;          // v f32
  float* P3   = P2 + 2097152;
  float* KVb  = P3 + 2097152;          // 2M: chunk states, then h (post-LN1) f32
  float* Ks   = KVb + 2097152;         // 32K chunk z
  float* smallP = Ks + 32768;          // 46080 f32 small params
  float* pend = smallP + 46080;
  int* flag = (int*)pend;
  u16* abf  = (u16*)(pend + 4);        // 2M: x / layer-out bf16
  u16* hbf  = abf  + 2097152;          // 2M: post-LN1 bf16
  u16* t1bf = hbf  + 2097152;          // 2M: attn out bf16
  u16* fbf  = t1bf + 2097152;          // 8M: ffn hidden bf16
  u16* qpbf = fbf  + 8388608;          // 2M: Q-phi bf16
  u16* kpbf = qpbf + 2097152;          // 2M: K-phi bf16
  u16* WtQ  = kpbf + 2097152;          // 12M: QKVO transposed, all layers
  u16* WtF1 = WtQ  + 12582912;         // 12M: FFN1 transposed, all layers
  u16* WtF2 = WtF1 + 12582912;         // 12M: FFN2 transposed, all layers

  float* bqF  = smallP + 0;
  float* boF  = smallP + 9216;
  float* omF  = smallP + 12288;
  float* l1gF = smallP + 18432;
  float* l1bF = smallP + 21504;
  float* l2gF = smallP + 24576;
  float* l2bF = smallP + 27648;
  float* bf1F = smallP + 30720;
  float* bf2F = smallP + 43008;

  detect_kernel<<<1, 64, 0, stream>>>((const u16*)d_in[10], flag);
  cvt_small<<<180, 256, 0, stream>>>(d_in[2], d_in[4], d_in[6], d_in[8], d_in[9],
                                     d_in[10], d_in[11], d_in[12], d_in[13],
                                     d_in[15], d_in[17], smallP, flag);
  cvt_x<<<8192, 256, 0, stream>>>(d_in[0], R, abf, 2097152, flag);

  // all weight transposes hoisted out of the layer loop
  transpose_cvtQ<<<dim3(32, 32, 12), 256, 0, stream>>>(d_in[1], d_in[3], d_in[5], d_in[7],
                                                       WtQ, flag);
  transpose_cvtL<<<dim3(128, 32, 3), 256, 0, stream>>>(d_in[14], WtF1, 1024, 4096,
                                                       4194304, 4194304, flag);
  transpose_cvtL<<<dim3(32, 128, 3), 256, 0, stream>>>(d_in[16], WtF2, 4096, 1024,
                                                       4194304, 4194304, flag);

  dim3 gQKV(8, 16, 3);    // 384 blocks (128x128 tiles)
  dim3 gO(8, 16, 2);      // 256 blocks, split-K z=2
  dim3 gF1(32, 16, 1);    // 512 blocks
  dim3 gF2(8, 16, 4);     // 512 blocks, split-K z=4

  for (int l = 0; l < 3; ++l){
    const size_t wQ = (size_t)l * 4194304;

    mfma_gemm<<<gQKV, 256, 0, stream>>>(abf, WtQ + wQ, bqF + l*1024, P0, (u16*)nullptr,
                                        1024, 1024, 0, 1024,
                                        1048576, 2097152, 3072, 1, 0);
    favor_kernel<<<8192, 256, 0, stream>>>(P0, P1, omF + l*2048, qpbf, kpbf);
    chunk_kv<<<512, 256, 0, stream>>>(P1, P2, KVb, Ks);
    chunk_scan<<<512, 256, 0, stream>>>(KVb, Ks);
    attn_kernel<<<512, 256, 0, stream>>>(qpbf, kpbf, P2, KVb, Ks, t1bf);

    mfma_gemm<<<gO, 256, 0, stream>>>(t1bf, WtQ + wQ + 3145728, boF + l*1024, P0, (u16*)nullptr,
                                      1024, 1024, 512, 512,
                                      0, 2097152, 0, 0, 0);
    resid_ln<<<2048, 256, 0, stream>>>(R, P0, P1, nullptr, nullptr,
                                       l1gF + l*1024, l1bF + l*1024,
                                       KVb, hbf, nullptr, flag);

    mfma_gemm<<<gF1, 256, 0, stream>>>(hbf, WtF1 + wQ, bf1F + l*4096, (float*)nullptr, fbf,
                                       4096, 1024, 0, 1024,
                                       0, 0, 0, 1, 1);

    mfma_gemm<<<gF2, 256, 0, stream>>>(fbf, WtF2 + wQ, bf2F + l*1024, P0, (u16*)nullptr,
                                       1024, 4096, 1024, 1024,
                                       0, 2097152, 0, 0, 0);

    resid_ln<<<2048, 256, 0, stream>>>(KVb, P0, P1, P2, P3,
                                       l2gF + l*1024, l2bF + l*1024,
                                       R, abf, (l == 2) ? d_out : nullptr, flag);
  }
}

// Round 4
// 727.521 us; speedup vs baseline: 1.1783x; 1.0806x over previous
//
#include <hip/hip_runtime.h>

typedef unsigned int u32;
typedef unsigned short u16;
typedef unsigned long long u64;

#define LN_EPS 1e-5f
#define ATTN_EPS 1e-6f

typedef __bf16 bf16x8 __attribute__((ext_vector_type(8)));
typedef short shortx8 __attribute__((ext_vector_type(8)));
typedef float fx4 __attribute__((ext_vector_type(4)));
typedef float fx16 __attribute__((ext_vector_type(16)));

__device__ __forceinline__ u16 f2bf(float f){
  union{float f; u32 u;} x; x.f = f;
  u32 r = 0x7fffu + ((x.u>>16)&1u);
  return (u16)((x.u + r)>>16);
}
__device__ __forceinline__ float bf2f(u16 u){
  union{u32 u; float f;} x; x.u = ((u32)u)<<16; return x.f;
}
__device__ __forceinline__ bf16x8 ldfrag(const u16* p){
  return __builtin_bit_cast(bf16x8, *(const shortx8*)p);
}

// ---------- async global->LDS 16B ----------
__device__ __forceinline__ void async16(const void* g, void* l){
  typedef const __attribute__((address_space(1))) void gas_t;
  typedef __attribute__((address_space(3))) void las_t;
  __builtin_amdgcn_global_load_lds((gas_t*)(u64)g, (las_t*)(u32)(u64)l, 16, 0, 0);
}

// ---------- dtype detect ----------
__global__ void detect_kernel(const u16* __restrict__ ln1g, int* __restrict__ flag){
  if (threadIdx.x == 0 && blockIdx.x == 0)
    *flag = (ln1g[0] == 0x3F80u) ? 1 : 0;
}

// ---------- all small params in one launch ----------
__global__ __launch_bounds__(256) void cvt_small(
    const void* p0, const void* p1, const void* p2, const void* p3,
    const void* p4, const void* p5, const void* p6, const void* p7,
    const void* p8, const void* p9, const void* p10,
    float* __restrict__ out, const int* __restrict__ flagp)
{
  int i = blockIdx.x*256 + threadIdx.x;
  if (i >= 46080) return;
  const void* src; int off;
  if      (i < 3072)  { src=p0;  off=i; }
  else if (i < 6144)  { src=p1;  off=i-3072; }
  else if (i < 9216)  { src=p2;  off=i-6144; }
  else if (i < 12288) { src=p3;  off=i-9216; }
  else if (i < 18432) { src=p4;  off=i-12288; }
  else if (i < 21504) { src=p5;  off=i-18432; }
  else if (i < 24576) { src=p6;  off=i-21504; }
  else if (i < 27648) { src=p7;  off=i-24576; }
  else if (i < 30720) { src=p8;  off=i-27648; }
  else if (i < 43008) { src=p9;  off=i-30720; }
  else                { src=p10; off=i-43008; }
  float v;
  if (*flagp){ union{u32 u; float f;} x; x.u = ((u32)((const u16*)src)[off])<<16; v = x.f; }
  else v = ((const float*)src)[off];
  out[i] = v;
}

// ---------- x convert: f32 + bf16 mirror ----------
__global__ __launch_bounds__(256) void cvt_x(const void* __restrict__ in, float* __restrict__ out,
                                             u16* __restrict__ outbf, int n, const int* __restrict__ flagp){
  int i = blockIdx.x*256 + threadIdx.x;
  if (i >= n) return;
  float v;
  if (*flagp){ union{u32 u; float f;} x; x.u = ((u32)((const u16*)in)[i])<<16; v = x.f; }
  else v = ((const float*)in)[i];
  out[i] = v;
  outbf[i] = f2bf(v);
}

// ---------- weight transpose + convert with layer z: W[K,N] -> Wt[N,K] bf16 ----------
__global__ __launch_bounds__(256) void transpose_cvtL(
    const void* __restrict__ W, u16* __restrict__ Wt,
    int K, int N, size_t zsrc, size_t zdst, const int* __restrict__ flagp)
{
  __shared__ float s[32][33];
  const size_t eoff = (size_t)blockIdx.z * zsrc;
  Wt += (size_t)blockIdx.z * zdst;
  const int bx = blockIdx.x, by = blockIdx.y;
  const int tid = threadIdx.x;
  const int c = tid & 31, r = tid >> 5;
  const int isbf = *flagp;
#pragma unroll
  for (int i = 0; i < 4; ++i){
    int k = by*32 + r + i*8, n = bx*32 + c;
    size_t idx = eoff + (size_t)k*N + n;
    float v;
    if (isbf){ union{u32 u; float f;} x; x.u = ((u32)((const u16*)W)[idx])<<16; v = x.f; }
    else v = ((const float*)W)[idx];
    s[r + i*8][c] = v;
  }
  __syncthreads();
#pragma unroll
  for (int i = 0; i < 4; ++i){
    int n = bx*32 + r + i*8, k = by*32 + c;
    Wt[(size_t)n*K + k] = f2bf(s[c][r + i*8]);
  }
}

// ---------- all 12 QKVO square transposes (3 layers x 4 mats) ----------
__global__ __launch_bounds__(256) void transpose_cvtQ(
    const void* __restrict__ W0, const void* __restrict__ W1,
    const void* __restrict__ W2, const void* __restrict__ W3,
    u16* __restrict__ Wt, const int* __restrict__ flagp)
{
  __shared__ float s[32][33];
  const int z = blockIdx.z, l = z >> 2, m = z & 3;
  const void* W = (m==0)?W0:((m==1)?W1:((m==2)?W2:W3));
  const size_t eoff = (size_t)l * 1048576;
  Wt += (size_t)z * 1048576;
  const int bx = blockIdx.x, by = blockIdx.y;
  const int tid = threadIdx.x;
  const int c = tid & 31, r = tid >> 5;
  const int isbf = *flagp;
#pragma unroll
  for (int i = 0; i < 4; ++i){
    int k = by*32 + r + i*8, n = bx*32 + c;
    size_t idx = eoff + (size_t)k*1024 + n;
    float v;
    if (isbf){ union{u32 u; float f;} x; x.u = ((u32)((const u16*)W)[idx])<<16; v = x.f; }
    else v = ((const float*)W)[idx];
    s[r + i*8][c] = v;
  }
  __syncthreads();
#pragma unroll
  for (int i = 0; i < 4; ++i){
    int n = bx*32 + r + i*8, k = by*32 + c;
    Wt[(size_t)n*1024 + k] = f2bf(s[c][r + i*8]);
  }
}

// ---------- 2-phase MFMA GEMM, 128x128 tile, BK=64, 2-buf, 256 thr ----------
// R10: T3 "minimum 2-phase" (m248 recipe). One barrier + one vmcnt(0) per 64-K
// (half the barrier events of the BK=32 3-buf). Rows are 128B -> full XOR-8
// swizzle (slot = kc ^ (row&7)) gives uniform bank use (4 lanes/quad) on the
// 32-lane column reads -> conflicts ~0. LDS dest stays LINEAR for
// global_load_lds (dest = base + tid*16B); the swizzle is applied on the
// GLOBAL source column (m173 / rule 21) and on the ds_read address.
// 32x32x16 MFMA, 4 waves, 64x64 per wave. LDS 64KB -> 2 blocks/CU.
__global__ __launch_bounds__(256, 2) void mfma_gemm(
    const u16* __restrict__ A, const u16* __restrict__ W,
    const float* __restrict__ bias,
    float* __restrict__ C, u16* __restrict__ Cbf,
    int N, int Kst, int kstep_z, int klen,
    size_t wz, size_t cz, int bz, int bias_all, int relu)
{
  __shared__ u16 As[2][128*64];
  __shared__ u16 Bs[2][128*64];
  const int z = blockIdx.z;
  W    += (size_t)z * wz;
  bias += (size_t)z * bz;
  if (C) C += (size_t)z * cz;
  const int kbeg = z * kstep_z;
  const int tid = threadIdx.x;
  const int lane = tid & 63, wid = tid >> 6;

  // ---- XCD-aware 2D chunk swizzle (8 XCDs as 4x2 grid of chunks) ----
  int bx = blockIdx.x, by = blockIdx.y;
  {
    const int gx = gridDim.x, gy = gridDim.y;
    if (((gx & 3) == 0) && ((gy & 1) == 0)) {
      const int cw = gx >> 2, ch = gy >> 1;
      if (((cw & (cw-1)) == 0) && ((ch & (ch-1)) == 0)) {
        const int o = by*gx + bx;
        const int xcd = o & 7, k = o >> 3;
        const int lgw = 31 - __clz(cw);
        bx = (xcd & 3)*cw + (k & (cw-1));
        by = (xcd >> 2)*ch + (k >> lgw);
      }
    }
  }
  const int row0 = by * 128, col0 = bx * 128;

  // ---- staging map: instr i (0..3) covers rows 32*i + (tid>>3); slot tid&7.
  // LDS dest elem = i*2048 + tid*8 (linear, 16B/lane). Slot s of row r holds
  // global k-chunk s ^ (r&7)  ->  source col = 8*((tid&7) ^ ((tid>>3)&7)).
  const int sR = tid >> 3;                       // 0..31
  const int sC = ((tid & 7) ^ (sR & 7)) << 3;    // elems
  const u16* gA = A + (size_t)(row0 + sR)*Kst + kbeg + sC;
  const u16* gB = W + (size_t)(col0 + sR)*Kst + kbeg + sC;
  const int lb = tid*8;

  const int iters = klen >> 6;
  // prologue: stage tile 0 into buf0
#pragma unroll
  for (int i = 0; i < 4; ++i){
    async16(gA + (size_t)(32*i)*Kst, &As[0][i*2048 + lb]);
    async16(gB + (size_t)(32*i)*Kst, &Bs[0][i*2048 + lb]);
  }
  __builtin_amdgcn_s_waitcnt(0x0F70);   // vmcnt(0)
  __builtin_amdgcn_s_barrier();

  const int l31 = lane & 31, hi = lane >> 5;
  const int wr = (wid >> 1) * 64, wc = (wid & 1) * 64;   // 2x2 waves, 64x64 each
  fx16 acc[2][2] = {};

  for (int t = 0; t < iters; ++t){
    const int cur = t & 1;
    if (t + 1 < iters){
      const int ko = (t + 1) << 6;
#pragma unroll
      for (int i = 0; i < 4; ++i){
        async16(gA + (size_t)(32*i)*Kst + ko, &As[cur^1][i*2048 + lb]);
        async16(gB + (size_t)(32*i)*Kst + ko, &Bs[cur^1][i*2048 + lb]);
      }
    }
    // frag reads: row = base + l31; k-chunk kc = 2*kh + hi lives at
    // slot kc ^ (row&7); elem = row*64 + slot*8. row&7 == l31&7.
    bf16x8 af0[4], af1[4], bg0[4], bg1[4];
#pragma unroll
    for (int kh = 0; kh < 4; ++kh){
      const int sl = (((2*kh + hi) ^ (l31 & 7))) << 3;
      af0[kh] = ldfrag(&As[cur][(wr      + l31)*64 + sl]);
      af1[kh] = ldfrag(&As[cur][(wr + 32 + l31)*64 + sl]);
      bg0[kh] = ldfrag(&Bs[cur][(wc      + l31)*64 + sl]);
      bg1[kh] = ldfrag(&Bs[cur][(wc + 32 + l31)*64 + sl]);
    }
    __builtin_amdgcn_s_setprio(1);
#pragma unroll
    for (int kh = 0; kh < 4; ++kh){
      acc[0][0] = __builtin_amdgcn_mfma_f32_32x32x16_bf16(af0[kh], bg0[kh], acc[0][0], 0,0,0);
      acc[0][1] = __builtin_amdgcn_mfma_f32_32x32x16_bf16(af0[kh], bg1[kh], acc[0][1], 0,0,0);
      acc[1][0] = __builtin_amdgcn_mfma_f32_32x32x16_bf16(af1[kh], bg0[kh], acc[1][0], 0,0,0);
      acc[1][1] = __builtin_amdgcn_mfma_f32_32x32x16_bf16(af1[kh], bg1[kh], acc[1][1], 0,0,0);
    }
    __builtin_amdgcn_s_setprio(0);
    __builtin_amdgcn_s_waitcnt(0x0F70);   // drain next-tile loads
    __builtin_amdgcn_s_barrier();         // all waves done reading cur; safe to overwrite
  }

  // C/D layout (32x32): col = lane&31, row = (r&3) + 8*(r>>2) + 4*(lane>>5)
  const int rbase = 4*hi;
#pragma unroll
  for (int nt = 0; nt < 2; ++nt){
    const int col = col0 + wc + nt*32 + l31;
    const float bv = (bias_all || z == 0) ? bias[col] : 0.f;
#pragma unroll
    for (int mt = 0; mt < 2; ++mt){
#pragma unroll
      for (int r = 0; r < 16; ++r){
        const int row = row0 + wr + mt*32 + rbase + (r & 3) + 8*(r >> 2);
        float v = acc[mt][nt][r] + bv;
        if (relu) v = fmaxf(v, 0.f);
        if (C)   C[(size_t)row*N + col] = v;
        if (Cbf) Cbf[(size_t)row*N + col] = f2bf(v);
      }
    }
  }
}

// ---------- FAVOR feature map; K phi -> f32 (for chunk_kv) ; Q,K phi -> bf16 mirrors ----------
__global__ __launch_bounds__(256) void favor_kernel(
    float* __restrict__ Q, float* __restrict__ Kp, const float* __restrict__ omega,
    u16* __restrict__ Qb, u16* __restrict__ Kb)
{
  __shared__ float sh[4][64];
  __shared__ float sho[64][32];
  int tid = threadIdx.x;
  for (int i = tid; i < 2048; i += 256)
    sho[i>>5][i&31] = omega[i];
  int wv = tid >> 6, lane = tid & 63;
  int th = blockIdx.x*4 + wv;
  size_t base = (size_t)(th >> 4) * 1024 + (size_t)(th & 15) * 64;
  int jm = lane & 31;
  float sgn = (lane < 32) ? 1.f : -1.f;
  for (int w = 0; w < 2; ++w){
    float* p = w ? Kp : Q;
    float xs = p[base + lane] * 0.35355339059327373f;
    __syncthreads();
    sh[wv][lane] = xs;
    __syncthreads();
    float u = 0.f, hh = 0.f;
#pragma unroll
    for (int d = 0; d < 64; ++d){
      float xv = sh[wv][d];
      u  = fmaf(xv, sho[d][jm], u);
      hh = fmaf(xv, xv, hh);
    }
    float phi = expf(sgn*u - 0.5f*hh) * 0.125f;
    if (w) p[base + lane] = phi;                 // K f32 kept for chunk_kv/Ksum
    (w ? Kb : Qb)[base + lane] = f2bf(phi);      // bf16 mirrors for MFMA attn
  }
}

// ---------- per-chunk KVt[d][m] = sum_j V[j][d] K[j][m], Ksum = sum_j k_j ----------
__global__ __launch_bounds__(256) void chunk_kv(
    const float* __restrict__ Kf, const float* __restrict__ V,
    float* __restrict__ KV, float* __restrict__ Ksum)
{
  __shared__ float Ks[64][64];
  __shared__ float Vs[64][64];
  int blk = blockIdx.x;
  int c = blk & 15, h = (blk >> 4) & 15, b = blk >> 8;
  int tid = threadIdx.x;
  for (int i = tid; i < 1024; i += 256){
    int j = i >> 4, m4 = (i & 15) << 2;
    size_t src = ((size_t)(b*1024 + c*64 + j)*16 + h)*64 + m4;
    *(float4*)&Ks[j][m4] = *(const float4*)&Kf[src];
    *(float4*)&Vs[j][m4] = *(const float4*)&V[src];
  }
  __syncthreads();
  int m = tid & 63, dg = tid >> 6;    // lane = m (coalesced KVt writes), wave-uniform d-group
  float acc[16] = {0.f};
  for (int j = 0; j < 64; ++j){
    float kv = Ks[j][m];
#pragma unroll
    for (int di = 0; di < 16; ++di)
      acc[di] = fmaf(Vs[j][dg*16+di], kv, acc[di]);
  }
  size_t outb = (size_t)blk * 4096;
#pragma unroll
  for (int di = 0; di < 16; ++di)
    KV[outb + (size_t)(dg*16+di)*64 + m] = acc[di];   // KVt[d][m]
  if (tid < 64){
    float s = 0.f;
    for (int j = 0; j < 64; ++j) s += Ks[j][tid];
    Ksum[(size_t)blk*64 + tid] = s;
  }
}

// ---------- exclusive prefix over chunks (elementwise; layout-agnostic) ----------
__global__ __launch_bounds__(256) void chunk_scan(float* __restrict__ KV, float* __restrict__ Ksum)
{
  int blk = blockIdx.x;
  int bh = blk >> 4, ec = blk & 15;
  int e = ec*256 + threadIdx.x;
  size_t base = (size_t)bh * 65536 + e;
  float run = 0.f;
  for (int c = 0; c < 16; ++c){
    size_t idx = base + (size_t)c*4096;
    float t = KV[idx]; KV[idx] = run; run += t;
  }
  if (ec == 0 && threadIdx.x < 64){
    size_t kb = (size_t)bh * 1024 + threadIdx.x;
    float rz = 0.f;
    for (int c = 0; c < 16; ++c){
      size_t idx = kb + c*64;
      float t = Ksum[idx]; Ksum[idx] = rz; rz += t;
    }
  }
}

// ---------- MFMA intra-chunk causal attention ----------
__global__ __launch_bounds__(256) void attn_kernel(
    const u16* __restrict__ Qbf, const u16* __restrict__ Kbf,
    const float* __restrict__ V, const float* __restrict__ KVt,
    const float* __restrict__ Ksum, u16* __restrict__ Outbf)
{
  __shared__ u16 Qs[64][72];
  __shared__ u16 Ks[64][72];
  __shared__ u16 Ss[64][72];
  __shared__ u16 Vt[64][72];
  __shared__ u16 Pt[64][72];
  __shared__ float Vrow[64][68];
  __shared__ float densum[64];

  const int blk = blockIdx.x;
  const int c = blk & 15, h = (blk >> 4) & 15, b = blk >> 8;
  const int tid = threadIdx.x;
  const int lane = tid & 63, w = tid >> 6;
  const int quad = lane >> 4, l16 = lane & 15;
  const int t0 = b*1024 + c*64;

  {
    const int r = tid >> 2, q4 = (tid & 3) << 4;   // 16 elems per thread
    size_t g = (size_t)(t0 + r)*1024 + h*64 + q4;
    *(uint4*)&Qs[r][q4]   = *(const uint4*)(Qbf + g);
    *(uint4*)&Qs[r][q4+8] = *(const uint4*)(Qbf + g + 8);
    *(uint4*)&Ks[r][q4]   = *(const uint4*)(Kbf + g);
    *(uint4*)&Ks[r][q4+8] = *(const uint4*)(Kbf + g + 8);
    const float* vg = V + g;
    *(float4*)&Vrow[r][q4+0]  = *(const float4*)(vg+0);
    *(float4*)&Vrow[r][q4+4]  = *(const float4*)(vg+4);
    *(float4*)&Vrow[r][q4+8]  = *(const float4*)(vg+8);
    *(float4*)&Vrow[r][q4+12] = *(const float4*)(vg+12);
    const float* pg = KVt + (size_t)blk*4096 + r*64 + q4;   // row d=r
    u16 tmp[16];
#pragma unroll
    for (int j = 0; j < 16; ++j) tmp[j] = f2bf(pg[j]);
    *(uint4*)&Pt[r][q4]   = *(uint4*)&tmp[0];
    *(uint4*)&Pt[r][q4+8] = *(uint4*)&tmp[8];
  }
  __syncthreads();
  {
    const int d = tid >> 2, j16 = (tid & 3) << 4;
    u16 tmp[16];
#pragma unroll
    for (int j = 0; j < 16; ++j) tmp[j] = f2bf(Vrow[j16+j][d]);
    *(uint4*)&Vt[d][j16]   = *(uint4*)&tmp[0];
    *(uint4*)&Vt[d][j16+8] = *(uint4*)&tmp[8];
  }

  const int iw0 = w*16;
  bf16x8 aq0 = ldfrag(&Qs[iw0+l16][quad*8]);
  bf16x8 aq1 = ldfrag(&Qs[iw0+l16][32+quad*8]);
  fx4 sacc[4];
#pragma unroll
  for (int u = 0; u < 4; ++u){
    sacc[u] = (fx4){0.f,0.f,0.f,0.f};
    bf16x8 b0 = ldfrag(&Ks[u*16+l16][quad*8]);
    bf16x8 b1 = ldfrag(&Ks[u*16+l16][32+quad*8]);
    sacc[u] = __builtin_amdgcn_mfma_f32_16x16x32_bf16(aq0, b0, sacc[u], 0, 0, 0);
    sacc[u] = __builtin_amdgcn_mfma_f32_16x16x32_bf16(aq1, b1, sacc[u], 0, 0, 0);
  }
  float rs[4] = {0.f,0.f,0.f,0.f};
#pragma unroll
  for (int u = 0; u < 4; ++u){
    const int jl = u*16 + l16;
#pragma unroll
    for (int r = 0; r < 4; ++r){
      const int il = iw0 + quad*4 + r;
      float v = (jl <= il) ? sacc[u][r] : 0.f;
      rs[r] += v;
      Ss[il][jl] = f2bf(v);
    }
  }
#pragma unroll
  for (int off = 1; off < 16; off <<= 1){
#pragma unroll
    for (int r = 0; r < 4; ++r) rs[r] += __shfl_xor(rs[r], off);
  }
  if (l16 == 0){
#pragma unroll
    for (int r = 0; r < 4; ++r) densum[iw0 + quad*4 + r] = rs[r];
  }
  __syncthreads();

  {
    const int row = iw0 + l16;
    const float* zp = Ksum + (size_t)blk*64;
    float dp = 0.f;
#pragma unroll
    for (int m = 0; m < 16; ++m){
      const int mm = quad*16 + m;
      dp = fmaf(bf2f(Qs[row][mm]), zp[mm], dp);
    }
    dp += __shfl_xor(dp, 16);
    dp += __shfl_xor(dp, 32);
    if (quad == 0) densum[row] = densum[row] + dp + ATTN_EPS;
  }
  __syncthreads();

  bf16x8 as0 = ldfrag(&Ss[iw0+l16][quad*8]);
  bf16x8 as1 = ldfrag(&Ss[iw0+l16][32+quad*8]);
  fx4 oacc[4];
#pragma unroll
  for (int u = 0; u < 4; ++u){
    const int d0 = u*16;
    oacc[u] = (fx4){0.f,0.f,0.f,0.f};
    oacc[u] = __builtin_amdgcn_mfma_f32_16x16x32_bf16(as0, ldfrag(&Vt[d0+l16][quad*8]),    oacc[u], 0,0,0);
    oacc[u] = __builtin_amdgcn_mfma_f32_16x16x32_bf16(as1, ldfrag(&Vt[d0+l16][32+quad*8]), oacc[u], 0,0,0);
    oacc[u] = __builtin_amdgcn_mfma_f32_16x16x32_bf16(aq0, ldfrag(&Pt[d0+l16][quad*8]),    oacc[u], 0,0,0);
    oacc[u] = __builtin_amdgcn_mfma_f32_16x16x32_bf16(aq1, ldfrag(&Pt[d0+l16][32+quad*8]), oacc[u], 0,0,0);
  }
#pragma unroll
  for (int u = 0; u < 4; ++u){
    const int d = u*16 + l16;
#pragma unroll
    for (int r = 0; r < 4; ++r){
      const int il = iw0 + quad*4 + r;
      const float o = oacc[u][r] / densum[il];
      Outbf[(size_t)(t0 + il)*1024 + h*64 + d] = f2bf(o);
    }
  }
}

// ---------- residual + LayerNorm: ln(X + Y0 + Y1 [+ Y2 + Y3]) ----------
__global__ __launch_bounds__(256) void resid_ln(
    const float* __restrict__ X, const float* __restrict__ Y0, const float* __restrict__ Y1,
    const float* __restrict__ Y2, const float* __restrict__ Y3,
    const float* __restrict__ g, const float* __restrict__ b,
    float* __restrict__ Dst, u16* __restrict__ DstBf,
    void* __restrict__ OutPtr, const int* __restrict__ flagp)
{
  __shared__ float rs[4], rss[4];
  int row = blockIdx.x, tid = threadIdx.x;
  int lane = tid & 63, wv = tid >> 6;
  size_t base = (size_t)row * 1024;
  int c = tid << 2;
  float4 xv = *(const float4*)&X[base + c];
  float4 y0 = *(const float4*)&Y0[base + c];
  float4 y1 = *(const float4*)&Y1[base + c];
  float v0 = xv.x+y0.x+y1.x, v1 = xv.y+y0.y+y1.y, v2 = xv.z+y0.z+y1.z, v3 = xv.w+y0.w+y1.w;
  if (Y2){
    float4 y2 = *(const float4*)&Y2[base + c];
    float4 y3 = *(const float4*)&Y3[base + c];
    v0 += y2.x + y3.x; v1 += y2.y + y3.y; v2 += y2.z + y3.z; v3 += y2.w + y3.w;
  }
  float s = v0+v1+v2+v3;
  float ss = v0*v0+v1*v1+v2*v2+v3*v3;
  for (int off = 32; off; off >>= 1){
    s  += __shfl_down(s, off);
    ss += __shfl_down(ss, off);
  }
  if (lane == 0){ rs[wv] = s; rss[wv] = ss; }
  __syncthreads();
  float S  = rs[0]+rs[1]+rs[2]+rs[3];
  float SS = rss[0]+rss[1]+rss[2]+rss[3];
  float mu = S * (1.f/1024.f);
  float var = SS * (1.f/1024.f) - mu*mu;
  float rinv = rsqrtf(var + LN_EPS);
  float4 gv = *(const float4*)(g + c);
  float4 bb = *(const float4*)(b + c);
  float o0 = (v0-mu)*rinv*gv.x + bb.x;
  float o1 = (v1-mu)*rinv*gv.y + bb.y;
  float o2 = (v2-mu)*rinv*gv.z + bb.z;
  float o3 = (v3-mu)*rinv*gv.w + bb.w;
  *(float4*)&Dst[base + c] = make_float4(o0,o1,o2,o3);
  uint2 ob;
  ob.x = (u32)f2bf(o0) | ((u32)f2bf(o1) << 16);
  ob.y = (u32)f2bf(o2) | ((u32)f2bf(o3) << 16);
  *(uint2*)(DstBf + base + c) = ob;
  if (OutPtr){
    if (*flagp){
      *(uint2*)((u16*)OutPtr + base + c) = ob;
    } else {
      *(float4*)((float*)OutPtr + base + c) = make_float4(o0,o1,o2,o3);
    }
  }
}

extern "C" void kernel_launch(void* const* d_in, const int* in_sizes, int n_in,
                              void* d_out, int out_size, void* d_ws, size_t ws_size,
                              hipStream_t stream)
{
  (void)in_sizes; (void)n_in; (void)out_size; (void)ws_size;

  float* ws   = (float*)d_ws;
  float* R    = ws;                    // 2M f32: x residual / layer input
  float* P0   = R  + 2097152;          // 4x2M contiguous: QKV out, split-K partials
  float* P1   = P0 + 2097152;
  float* P2   = P1 + 2097152;          // v f32
  float* P3   = P2 + 2097152;
  float* KVb  = P3 + 2097152;          // 2M: chunk states, then h (post-LN1) f32
  float* Ks   = KVb + 2097152;         // 32K chunk z
  float* smallP = Ks + 32768;          // 46080 f32 small params
  float* pend = smallP + 46080;
  int* flag = (int*)pend;
  u16* abf  = (u16*)(pend + 4);        // 2M: x / layer-out bf16
  u16* hbf  = abf  + 2097152;          // 2M: post-LN1 bf16
  u16* t1bf = hbf  + 2097152;          // 2M: attn out bf16
  u16* fbf  = t1bf + 2097152;          // 8M: ffn hidden bf16
  u16* qpbf = fbf  + 8388608;          // 2M: Q-phi bf16
  u16* kpbf = qpbf + 2097152;          // 2M: K-phi bf16
  u16* WtQ  = kpbf + 2097152;          // 12M: QKVO transposed, all layers
  u16* WtF1 = WtQ  + 12582912;         // 12M: FFN1 transposed, all layers
  u16* WtF2 = WtF1 + 12582912;         // 12M: FFN2 transposed, all layers

  float* bqF  = smallP + 0;
  float* boF  = smallP + 9216;
  float* omF  = smallP + 12288;
  float* l1gF = smallP + 18432;
  float* l1bF = smallP + 21504;
  float* l2gF = smallP + 24576;
  float* l2bF = smallP + 27648;
  float* bf1F = smallP + 30720;
  float* bf2F = smallP + 43008;

  detect_kernel<<<1, 64, 0, stream>>>((const u16*)d_in[10], flag);
  cvt_small<<<180, 256, 0, stream>>>(d_in[2], d_in[4], d_in[6], d_in[8], d_in[9],
                                     d_in[10], d_in[11], d_in[12], d_in[13],
                                     d_in[15], d_in[17], smallP, flag);
  cvt_x<<<8192, 256, 0, stream>>>(d_in[0], R, abf, 2097152, flag);

  // all weight transposes hoisted out of the layer loop
  transpose_cvtQ<<<dim3(32, 32, 12), 256, 0, stream>>>(d_in[1], d_in[3], d_in[5], d_in[7],
                                                       WtQ, flag);
  transpose_cvtL<<<dim3(128, 32, 3), 256, 0, stream>>>(d_in[14], WtF1, 1024, 4096,
                                                       4194304, 4194304, flag);
  transpose_cvtL<<<dim3(32, 128, 3), 256, 0, stream>>>(d_in[16], WtF2, 4096, 1024,
                                                       4194304, 4194304, flag);

  dim3 gQKV(8, 16, 3);    // 384 blocks (128x128 tiles)
  dim3 gO(8, 16, 2);      // 256 blocks, split-K z=2
  dim3 gF1(32, 16, 1);    // 512 blocks
  dim3 gF2(8, 16, 4);     // 512 blocks, split-K z=4

  for (int l = 0; l < 3; ++l){
    const size_t wQ = (size_t)l * 4194304;

    mfma_gemm<<<gQKV, 256, 0, stream>>>(abf, WtQ + wQ, bqF + l*1024, P0, (u16*)nullptr,
                                        1024, 1024, 0, 1024,
                                        1048576, 2097152, 3072, 1, 0);
    favor_kernel<<<8192, 256, 0, stream>>>(P0, P1, omF + l*2048, qpbf, kpbf);
    chunk_kv<<<512, 256, 0, stream>>>(P1, P2, KVb, Ks);
    chunk_scan<<<512, 256, 0, stream>>>(KVb, Ks);
    attn_kernel<<<512, 256, 0, stream>>>(qpbf, kpbf, P2, KVb, Ks, t1bf);

    mfma_gemm<<<gO, 256, 0, stream>>>(t1bf, WtQ + wQ + 3145728, boF + l*1024, P0, (u16*)nullptr,
                                      1024, 1024, 512, 512,
                                      0, 2097152, 0, 0, 0);
    resid_ln<<<2048, 256, 0, stream>>>(R, P0, P1, nullptr, nullptr,
                                       l1gF + l*1024, l1bF + l*1024,
                                       KVb, hbf, nullptr, flag);

    mfma_gemm<<<gF1, 256, 0, stream>>>(hbf, WtF1 + wQ, bf1F + l*4096, (float*)nullptr, fbf,
                                       4096, 1024, 0, 1024,
                                       0, 0, 0, 1, 1);

    mfma_gemm<<<gF2, 256, 0, stream>>>(fbf, WtF2 + wQ, bf2F + l*1024, P0, (u16*)nullptr,
                                       1024, 4096, 1024, 1024,
                                       0, 2097152, 0, 0, 0);

    resid_ln<<<2048, 256, 0, stream>>>(KVb, P0, P1, P2, P3,
                                       l2gF + l*1024, l2bF + l*1024,
                                       R, abf, (l == 2) ? d_out : nullptr, flag);
  }
}

// Round 5
// 721.343 us; speedup vs baseline: 1.1883x; 1.0086x over previous
//
#include <hip/hip_runtime.h>

typedef unsigned int u32;
typedef unsigned short u16;
typedef unsigned long long u64;

#define LN_EPS 1e-5f
#define ATTN_EPS 1e-6f

typedef __bf16 bf16x8 __attribute__((ext_vector_type(8)));
typedef short shortx8 __attribute__((ext_vector_type(8)));
typedef float fx4 __attribute__((ext_vector_type(4)));
typedef float fx16 __attribute__((ext_vector_type(16)));

__device__ __forceinline__ u16 f2bf(float f){
  union{float f; u32 u;} x; x.f = f;
  u32 r = 0x7fffu + ((x.u>>16)&1u);
  return (u16)((x.u + r)>>16);
}
__device__ __forceinline__ float bf2f(u16 u){
  union{u32 u; float f;} x; x.u = ((u32)u)<<16; return x.f;
}
__device__ __forceinline__ bf16x8 ldfrag(const u16* p){
  return __builtin_bit_cast(bf16x8, *(const shortx8*)p);
}

// ---------- async global->LDS 16B ----------
__device__ __forceinline__ void async16(const void* g, void* l){
  typedef const __attribute__((address_space(1))) void gas_t;
  typedef __attribute__((address_space(3))) void las_t;
  __builtin_amdgcn_global_load_lds((gas_t*)(u64)g, (las_t*)(u32)(u64)l, 16, 0, 0);
}

// ---------- dtype detect ----------
__global__ void detect_kernel(const u16* __restrict__ ln1g, int* __restrict__ flag){
  if (threadIdx.x == 0 && blockIdx.x == 0)
    *flag = (ln1g[0] == 0x3F80u) ? 1 : 0;
}

// ---------- all small params in one launch ----------
__global__ __launch_bounds__(256) void cvt_small(
    const void* p0, const void* p1, const void* p2, const void* p3,
    const void* p4, const void* p5, const void* p6, const void* p7,
    const void* p8, const void* p9, const void* p10,
    float* __restrict__ out, const int* __restrict__ flagp)
{
  int i = blockIdx.x*256 + threadIdx.x;
  if (i >= 46080) return;
  const void* src; int off;
  if      (i < 3072)  { src=p0;  off=i; }
  else if (i < 6144)  { src=p1;  off=i-3072; }
  else if (i < 9216)  { src=p2;  off=i-6144; }
  else if (i < 12288) { src=p3;  off=i-9216; }
  else if (i < 18432) { src=p4;  off=i-12288; }
  else if (i < 21504) { src=p5;  off=i-18432; }
  else if (i < 24576) { src=p6;  off=i-21504; }
  else if (i < 27648) { src=p7;  off=i-24576; }
  else if (i < 30720) { src=p8;  off=i-27648; }
  else if (i < 43008) { src=p9;  off=i-30720; }
  else                { src=p10; off=i-43008; }
  float v;
  if (*flagp){ union{u32 u; float f;} x; x.u = ((u32)((const u16*)src)[off])<<16; v = x.f; }
  else v = ((const float*)src)[off];
  out[i] = v;
}

// ---------- x convert: f32 + bf16 mirror ----------
__global__ __launch_bounds__(256) void cvt_x(const void* __restrict__ in, float* __restrict__ out,
                                             u16* __restrict__ outbf, int n, const int* __restrict__ flagp){
  int i = blockIdx.x*256 + threadIdx.x;
  if (i >= n) return;
  float v;
  if (*flagp){ union{u32 u; float f;} x; x.u = ((u32)((const u16*)in)[i])<<16; v = x.f; }
  else v = ((const float*)in)[i];
  out[i] = v;
  outbf[i] = f2bf(v);
}

// ---------- weight transpose + convert with layer z: W[K,N] -> Wt[N,K] bf16 ----------
__global__ __launch_bounds__(256) void transpose_cvtL(
    const void* __restrict__ W, u16* __restrict__ Wt,
    int K, int N, size_t zsrc, size_t zdst, const int* __restrict__ flagp)
{
  __shared__ float s[32][33];
  const size_t eoff = (size_t)blockIdx.z * zsrc;
  Wt += (size_t)blockIdx.z * zdst;
  const int bx = blockIdx.x, by = blockIdx.y;
  const int tid = threadIdx.x;
  const int c = tid & 31, r = tid >> 5;
  const int isbf = *flagp;
#pragma unroll
  for (int i = 0; i < 4; ++i){
    int k = by*32 + r + i*8, n = bx*32 + c;
    size_t idx = eoff + (size_t)k*N + n;
    float v;
    if (isbf){ union{u32 u; float f;} x; x.u = ((u32)((const u16*)W)[idx])<<16; v = x.f; }
    else v = ((const float*)W)[idx];
    s[r + i*8][c] = v;
  }
  __syncthreads();
#pragma unroll
  for (int i = 0; i < 4; ++i){
    int n = bx*32 + r + i*8, k = by*32 + c;
    Wt[(size_t)n*K + k] = f2bf(s[c][r + i*8]);
  }
}

// ---------- all 12 QKVO square transposes (3 layers x 4 mats) ----------
__global__ __launch_bounds__(256) void transpose_cvtQ(
    const void* __restrict__ W0, const void* __restrict__ W1,
    const void* __restrict__ W2, const void* __restrict__ W3,
    u16* __restrict__ Wt, const int* __restrict__ flagp)
{
  __shared__ float s[32][33];
  const int z = blockIdx.z, l = z >> 2, m = z & 3;
  const void* W = (m==0)?W0:((m==1)?W1:((m==2)?W2:W3));
  const size_t eoff = (size_t)l * 1048576;
  Wt += (size_t)z * 1048576;
  const int bx = blockIdx.x, by = blockIdx.y;
  const int tid = threadIdx.x;
  const int c = tid & 31, r = tid >> 5;
  const int isbf = *flagp;
#pragma unroll
  for (int i = 0; i < 4; ++i){
    int k = by*32 + r + i*8, n = bx*32 + c;
    size_t idx = eoff + (size_t)k*1024 + n;
    float v;
    if (isbf){ union{u32 u; float f;} x; x.u = ((u32)((const u16*)W)[idx])<<16; v = x.f; }
    else v = ((const float*)W)[idx];
    s[r + i*8][c] = v;
  }
  __syncthreads();
#pragma unroll
  for (int i = 0; i < 4; ++i){
    int n = bx*32 + r + i*8, k = by*32 + c;
    Wt[(size_t)n*1024 + k] = f2bf(s[c][r + i*8]);
  }
}

// ---------- 8-phase-style MFMA GEMM: 256x128 tile, BK=64, TRIPLE buffer ----------
// R11 (T3+T4+T5 port): 512 thr / 8 waves (4Mx2N), 64x64 per wave, 32x32x16 MFMA.
// K-step t computes from buf[t%3] while staging step t+2 into buf[(t+2)%3]
// (that buffer's readers finished at the end-of-(t-1) barrier -> race-free).
// Counted wait: at end of step t, outstanding <= 12 loads (t+1's 6 + t+2's 6);
// vmcnt(6) retires all of t+1 and leaves t+2's 6 IN FLIGHT across the barrier
// (T4: never vmcnt(0) in the main loop). Each K-step = 2 sub-phases
// {8 ds_read_b128 | 3 global_load_lds -> barrier -> setprio(1) 8 MFMA -> barrier}.
// LDS swizzle (R10-verified): rows 128B = 8 slots of 16B; k-chunk kc of row r
// at slot kc^(r&7); linear gload_lds dest + inverse-permuted global source.
__global__ __launch_bounds__(512, 2) void mfma_gemm8(
    const u16* __restrict__ A, const u16* __restrict__ W,
    const float* __restrict__ bias,
    float* __restrict__ C, u16* __restrict__ Cbf,
    int N, int Kst, int kstep_z, int klen,
    size_t wz, size_t cz, int bz, int bias_all, int relu)
{
  __shared__ u16 As[3][256*64];   // 96 KB
  __shared__ u16 Bs[3][128*64];   // 48 KB
  const int z = blockIdx.z;
  W    += (size_t)z * wz;
  bias += (size_t)z * bz;
  if (C) C += (size_t)z * cz;
  const int kbeg = z * kstep_z;
  const int tid = threadIdx.x;
  const int lane = tid & 63, wid = tid >> 6;
  const size_t KstS = (size_t)Kst;

  // ---- XCD-aware 2D chunk swizzle (8 XCDs as 4x2 grid of chunks) ----
  int bx = blockIdx.x, by = blockIdx.y;
  {
    const int gx = gridDim.x, gy = gridDim.y;
    if (((gx & 3) == 0) && ((gy & 1) == 0)) {
      const int cw = gx >> 2, ch = gy >> 1;
      if (((cw & (cw-1)) == 0) && ((ch & (ch-1)) == 0)) {
        const int o = by*gx + bx;
        const int xcd = o & 7, k = o >> 3;
        const int lgw = 31 - __clz(cw);
        bx = (xcd & 3)*cw + (k & (cw-1));
        by = (xcd >> 2)*ch + (k >> lgw);
      }
    }
  }
  const int row0 = by * 256, col0 = bx * 128;

  // staging: round i covers rows i*64 + (tid>>3), slot tid&7; LDS elem = i*4096 + tid*8
  // (wave-uniform base + lane-contiguous 16B). Source k-chunk = slot ^ (row&7).
  const int sR = tid >> 3;
  const int sC = ((tid & 7) ^ (sR & 7)) << 3;
  const u16* gAr = A + (size_t)(row0 + sR)*KstS + kbeg + sC;   // A rounds 0..3 (+64*i rows)
  const u16* gBr = W + (size_t)(col0 + sR)*KstS + kbeg + sC;   // B rounds 0..1

#define STAGE_H0(b, ks) { const size_t ko = (size_t)(ks) << 6; \
    async16(gAr + ko,                &As[b][tid*8]); \
    async16(gAr + 64*KstS + ko,      &As[b][4096 + tid*8]); \
    async16(gBr + ko,                &Bs[b][tid*8]); }
#define STAGE_H1(b, ks) { const size_t ko = (size_t)(ks) << 6; \
    async16(gAr + 128*KstS + ko,     &As[b][8192 + tid*8]); \
    async16(gAr + 192*KstS + ko,     &As[b][12288 + tid*8]); \
    async16(gBr + 64*KstS + ko,      &Bs[b][4096 + tid*8]); }

  const int nt = klen >> 6;
  // prologue: steps 0 and 1 fully issued (12 loads); vmcnt(6) -> step 0 landed
  STAGE_H0(0, 0) STAGE_H1(0, 0)
  STAGE_H0(1, 1) STAGE_H1(1, 1)
  __builtin_amdgcn_s_waitcnt(0x0F76);   // vmcnt(6)
  __builtin_amdgcn_s_barrier();

  const int l31 = lane & 31, hi = lane >> 5;
  const int wr = (wid >> 1) * 64;        // 4 M-blocks of 64 rows
  const int wc = (wid & 1) * 64;         // 2 N-blocks of 64 cols
  fx16 acc[2][2] = {};

  for (int t = 0; t < nt; ++t){
    const int buf = t % 3;
    const int nx   = (t + 2 < nt) ? (t + 2) : (nt - 1);  // clamped (tail writes unused buf)
    const int nbuf = (t + 2) % 3;

    // ---------- sub-phase 0: kh = 0,1 ----------
    bf16x8 a0[2][2], b0[2][2];          // [mt/nt][kk]
#pragma unroll
    for (int kk = 0; kk < 2; ++kk){
      const int sl = ((2*kk + hi) ^ (l31 & 7)) << 3;     // kh = kk
#pragma unroll
      for (int mt = 0; mt < 2; ++mt)
        a0[mt][kk] = ldfrag(&As[buf][(wr + mt*32 + l31)*64 + sl]);
#pragma unroll
      for (int ntc = 0; ntc < 2; ++ntc)
        b0[ntc][kk] = ldfrag(&Bs[buf][(wc + ntc*32 + l31)*64 + sl]);
    }
    STAGE_H0(nbuf, nx)
    __builtin_amdgcn_s_barrier();
    __builtin_amdgcn_s_setprio(1);
#pragma unroll
    for (int kk = 0; kk < 2; ++kk)
#pragma unroll
      for (int mt = 0; mt < 2; ++mt)
#pragma unroll
        for (int ntc = 0; ntc < 2; ++ntc)
          acc[mt][ntc] = __builtin_amdgcn_mfma_f32_32x32x16_bf16(a0[mt][kk], b0[ntc][kk], acc[mt][ntc], 0,0,0);
    __builtin_amdgcn_s_setprio(0);
    __builtin_amdgcn_s_barrier();

    // ---------- sub-phase 1: kh = 2,3 ----------
    bf16x8 a1[2][2], b1[2][2];
#pragma unroll
    for (int kk = 0; kk < 2; ++kk){
      const int sl = ((2*(kk+2) + hi) ^ (l31 & 7)) << 3; // kh = kk+2
#pragma unroll
      for (int mt = 0; mt < 2; ++mt)
        a1[mt][kk] = ldfrag(&As[buf][(wr + mt*32 + l31)*64 + sl]);
#pragma unroll
      for (int ntc = 0; ntc < 2; ++ntc)
        b1[ntc][kk] = ldfrag(&Bs[buf][(wc + ntc*32 + l31)*64 + sl]);
    }
    STAGE_H1(nbuf, nx)
    __builtin_amdgcn_s_waitcnt(0x0F76);   // vmcnt(6): t+1 fully landed, t+2 in flight
    __builtin_amdgcn_s_barrier();
    __builtin_amdgcn_s_setprio(1);
#pragma unroll
    for (int kk = 0; kk < 2; ++kk)
#pragma unroll
      for (int mt = 0; mt < 2; ++mt)
#pragma unroll
        for (int ntc = 0; ntc < 2; ++ntc)
          acc[mt][ntc] = __builtin_amdgcn_mfma_f32_32x32x16_bf16(a1[mt][kk], b1[ntc][kk], acc[mt][ntc], 0,0,0);
    __builtin_amdgcn_s_setprio(0);
    __builtin_amdgcn_s_barrier();
  }
  __builtin_amdgcn_s_waitcnt(0x0F70);     // drain tail staging before LDS dealloc

  // C/D layout (32x32): col = lane&31, row = (r&3) + 8*(r>>2) + 4*(lane>>5)
  const int rbase = 4*hi;
#pragma unroll
  for (int ntc = 0; ntc < 2; ++ntc){
    const int col = col0 + wc + ntc*32 + l31;
    const float bv = (bias_all || z == 0) ? bias[col] : 0.f;
#pragma unroll
    for (int mt = 0; mt < 2; ++mt){
#pragma unroll
      for (int r = 0; r < 16; ++r){
        const int row = row0 + wr + mt*32 + rbase + (r & 3) + 8*(r >> 2);
        float v = acc[mt][ntc][r] + bv;
        if (relu) v = fmaxf(v, 0.f);
        if (C)   C[(size_t)row*N + col] = v;
        if (Cbf) Cbf[(size_t)row*N + col] = f2bf(v);
      }
    }
  }
#undef STAGE_H0
#undef STAGE_H1
}

// ---------- FAVOR feature map; K phi -> f32 (for chunk_kv) ; Q,K phi -> bf16 mirrors ----------
__global__ __launch_bounds__(256) void favor_kernel(
    float* __restrict__ Q, float* __restrict__ Kp, const float* __restrict__ omega,
    u16* __restrict__ Qb, u16* __restrict__ Kb)
{
  __shared__ float sh[4][64];
  __shared__ float sho[64][32];
  int tid = threadIdx.x;
  for (int i = tid; i < 2048; i += 256)
    sho[i>>5][i&31] = omega[i];
  int wv = tid >> 6, lane = tid & 63;
  int th = blockIdx.x*4 + wv;
  size_t base = (size_t)(th >> 4) * 1024 + (size_t)(th & 15) * 64;
  int jm = lane & 31;
  float sgn = (lane < 32) ? 1.f : -1.f;
  for (int w = 0; w < 2; ++w){
    float* p = w ? Kp : Q;
    float xs = p[base + lane] * 0.35355339059327373f;
    __syncthreads();
    sh[wv][lane] = xs;
    __syncthreads();
    float u = 0.f, hh = 0.f;
#pragma unroll
    for (int d = 0; d < 64; ++d){
      float xv = sh[wv][d];
      u  = fmaf(xv, sho[d][jm], u);
      hh = fmaf(xv, xv, hh);
    }
    float phi = expf(sgn*u - 0.5f*hh) * 0.125f;
    if (w) p[base + lane] = phi;                 // K f32 kept for chunk_kv/Ksum
    (w ? Kb : Qb)[base + lane] = f2bf(phi);      // bf16 mirrors for MFMA attn
  }
}

// ---------- per-chunk KVt[d][m] = sum_j V[j][d] K[j][m], Ksum = sum_j k_j ----------
__global__ __launch_bounds__(256) void chunk_kv(
    const float* __restrict__ Kf, const float* __restrict__ V,
    float* __restrict__ KV, float* __restrict__ Ksum)
{
  __shared__ float Ks[64][64];
  __shared__ float Vs[64][64];
  int blk = blockIdx.x;
  int c = blk & 15, h = (blk >> 4) & 15, b = blk >> 8;
  int tid = threadIdx.x;
  for (int i = tid; i < 1024; i += 256){
    int j = i >> 4, m4 = (i & 15) << 2;
    size_t src = ((size_t)(b*1024 + c*64 + j)*16 + h)*64 + m4;
    *(float4*)&Ks[j][m4] = *(const float4*)&Kf[src];
    *(float4*)&Vs[j][m4] = *(const float4*)&V[src];
  }
  __syncthreads();
  int m = tid & 63, dg = tid >> 6;    // lane = m (coalesced KVt writes), wave-uniform d-group
  float acc[16] = {0.f};
  for (int j = 0; j < 64; ++j){
    float kv = Ks[j][m];
#pragma unroll
    for (int di = 0; di < 16; ++di)
      acc[di] = fmaf(Vs[j][dg*16+di], kv, acc[di]);
  }
  size_t outb = (size_t)blk * 4096;
#pragma unroll
  for (int di = 0; di < 16; ++di)
    KV[outb + (size_t)(dg*16+di)*64 + m] = acc[di];   // KVt[d][m]
  if (tid < 64){
    float s = 0.f;
    for (int j = 0; j < 64; ++j) s += Ks[j][tid];
    Ksum[(size_t)blk*64 + tid] = s;
  }
}

// ---------- exclusive prefix over chunks (elementwise; layout-agnostic) ----------
__global__ __launch_bounds__(256) void chunk_scan(float* __restrict__ KV, float* __restrict__ Ksum)
{
  int blk = blockIdx.x;
  int bh = blk >> 4, ec = blk & 15;
  int e = ec*256 + threadIdx.x;
  size_t base = (size_t)bh * 65536 + e;
  float run = 0.f;
  for (int c = 0; c < 16; ++c){
    size_t idx = base + (size_t)c*4096;
    float t = KV[idx]; KV[idx] = run; run += t;
  }
  if (ec == 0 && threadIdx.x < 64){
    size_t kb = (size_t)bh * 1024 + threadIdx.x;
    float rz = 0.f;
    for (int c = 0; c < 16; ++c){
      size_t idx = kb + c*64;
      float t = Ksum[idx]; Ksum[idx] = rz; rz += t;
    }
  }
}

// ---------- MFMA intra-chunk causal attention ----------
__global__ __launch_bounds__(256) void attn_kernel(
    const u16* __restrict__ Qbf, const u16* __restrict__ Kbf,
    const float* __restrict__ V, const float* __restrict__ KVt,
    const float* __restrict__ Ksum, u16* __restrict__ Outbf)
{
  __shared__ u16 Qs[64][72];
  __shared__ u16 Ks[64][72];
  __shared__ u16 Ss[64][72];
  __shared__ u16 Vt[64][72];
  __shared__ u16 Pt[64][72];
  __shared__ float Vrow[64][68];
  __shared__ float densum[64];

  const int blk = blockIdx.x;
  const int c = blk & 15, h = (blk >> 4) & 15, b = blk >> 8;
  const int tid = threadIdx.x;
  const int lane = tid & 63, w = tid >> 6;
  const int quad = lane >> 4, l16 = lane & 15;
  const int t0 = b*1024 + c*64;

  {
    const int r = tid >> 2, q4 = (tid & 3) << 4;   // 16 elems per thread
    size_t g = (size_t)(t0 + r)*1024 + h*64 + q4;
    *(uint4*)&Qs[r][q4]   = *(const uint4*)(Qbf + g);
    *(uint4*)&Qs[r][q4+8] = *(const uint4*)(Qbf + g + 8);
    *(uint4*)&Ks[r][q4]   = *(const uint4*)(Kbf + g);
    *(uint4*)&Ks[r][q4+8] = *(const uint4*)(Kbf + g + 8);
    const float* vg = V + g;
    *(float4*)&Vrow[r][q4+0]  = *(const float4*)(vg+0);
    *(float4*)&Vrow[r][q4+4]  = *(const float4*)(vg+4);
    *(float4*)&Vrow[r][q4+8]  = *(const float4*)(vg+8);
    *(float4*)&Vrow[r][q4+12] = *(const float4*)(vg+12);
    const float* pg = KVt + (size_t)blk*4096 + r*64 + q4;   // row d=r
    u16 tmp[16];
#pragma unroll
    for (int j = 0; j < 16; ++j) tmp[j] = f2bf(pg[j]);
    *(uint4*)&Pt[r][q4]   = *(uint4*)&tmp[0];
    *(uint4*)&Pt[r][q4+8] = *(uint4*)&tmp[8];
  }
  __syncthreads();
  {
    const int d = tid >> 2, j16 = (tid & 3) << 4;
    u16 tmp[16];
#pragma unroll
    for (int j = 0; j < 16; ++j) tmp[j] = f2bf(Vrow[j16+j][d]);
    *(uint4*)&Vt[d][j16]   = *(uint4*)&tmp[0];
    *(uint4*)&Vt[d][j16+8] = *(uint4*)&tmp[8];
  }

  const int iw0 = w*16;
  bf16x8 aq0 = ldfrag(&Qs[iw0+l16][quad*8]);
  bf16x8 aq1 = ldfrag(&Qs[iw0+l16][32+quad*8]);
  fx4 sacc[4];
#pragma unroll
  for (int u = 0; u < 4; ++u){
    sacc[u] = (fx4){0.f,0.f,0.f,0.f};
    bf16x8 b0 = ldfrag(&Ks[u*16+l16][quad*8]);
    bf16x8 b1 = ldfrag(&Ks[u*16+l16][32+quad*8]);
    sacc[u] = __builtin_amdgcn_mfma_f32_16x16x32_bf16(aq0, b0, sacc[u], 0, 0, 0);
    sacc[u] = __builtin_amdgcn_mfma_f32_16x16x32_bf16(aq1, b1, sacc[u], 0, 0, 0);
  }
  float rs[4] = {0.f,0.f,0.f,0.f};
#pragma unroll
  for (int u = 0; u < 4; ++u){
    const int jl = u*16 + l16;
#pragma unroll
    for (int r = 0; r < 4; ++r){
      const int il = iw0 + quad*4 + r;
      float v = (jl <= il) ? sacc[u][r] : 0.f;
      rs[r] += v;
      Ss[il][jl] = f2bf(v);
    }
  }
#pragma unroll
  for (int off = 1; off < 16; off <<= 1){
#pragma unroll
    for (int r = 0; r < 4; ++r) rs[r] += __shfl_xor(rs[r], off);
  }
  if (l16 == 0){
#pragma unroll
    for (int r = 0; r < 4; ++r) densum[iw0 + quad*4 + r] = rs[r];
  }
  __syncthreads();

  {
    const int row = iw0 + l16;
    const float* zp = Ksum + (size_t)blk*64;
    float dp = 0.f;
#pragma unroll
    for (int m = 0; m < 16; ++m){
      const int mm = quad*16 + m;
      dp = fmaf(bf2f(Qs[row][mm]), zp[mm], dp);
    }
    dp += __shfl_xor(dp, 16);
    dp += __shfl_xor(dp, 32);
    if (quad == 0) densum[row] = densum[row] + dp + ATTN_EPS;
  }
  __syncthreads();

  bf16x8 as0 = ldfrag(&Ss[iw0+l16][quad*8]);
  bf16x8 as1 = ldfrag(&Ss[iw0+l16][32+quad*8]);
  fx4 oacc[4];
#pragma unroll
  for (int u = 0; u < 4; ++u){
    const int d0 = u*16;
    oacc[u] = (fx4){0.f,0.f,0.f,0.f};
    oacc[u] = __builtin_amdgcn_mfma_f32_16x16x32_bf16(as0, ldfrag(&Vt[d0+l16][quad*8]),    oacc[u], 0,0,0);
    oacc[u] = __builtin_amdgcn_mfma_f32_16x16x32_bf16(as1, ldfrag(&Vt[d0+l16][32+quad*8]), oacc[u], 0,0,0);
    oacc[u] = __builtin_amdgcn_mfma_f32_16x16x32_bf16(aq0, ldfrag(&Pt[d0+l16][quad*8]),    oacc[u], 0,0,0);
    oacc[u] = __builtin_amdgcn_mfma_f32_16x16x32_bf16(aq1, ldfrag(&Pt[d0+l16][32+quad*8]), oacc[u], 0,0,0);
  }
#pragma unroll
  for (int u = 0; u < 4; ++u){
    const int d = u*16 + l16;
#pragma unroll
    for (int r = 0; r < 4; ++r){
      const int il = iw0 + quad*4 + r;
      const float o = oacc[u][r] / densum[il];
      Outbf[(size_t)(t0 + il)*1024 + h*64 + d] = f2bf(o);
    }
  }
}

// ---------- residual + LayerNorm: ln(X + Y0 + Y1 [+ Y2 + Y3]) ----------
__global__ __launch_bounds__(256) void resid_ln(
    const float* __restrict__ X, const float* __restrict__ Y0, const float* __restrict__ Y1,
    const float* __restrict__ Y2, const float* __restrict__ Y3,
    const float* __restrict__ g, const float* __restrict__ b,
    float* __restrict__ Dst, u16* __restrict__ DstBf,
    void* __restrict__ OutPtr, const int* __restrict__ flagp)
{
  __shared__ float rs[4], rss[4];
  int row = blockIdx.x, tid = threadIdx.x;
  int lane = tid & 63, wv = tid >> 6;
  size_t base = (size_t)row * 1024;
  int c = tid << 2;
  float4 xv = *(const float4*)&X[base + c];
  float4 y0 = *(const float4*)&Y0[base + c];
  float4 y1 = *(const float4*)&Y1[base + c];
  float v0 = xv.x+y0.x+y1.x, v1 = xv.y+y0.y+y1.y, v2 = xv.z+y0.z+y1.z, v3 = xv.w+y0.w+y1.w;
  if (Y2){
    float4 y2 = *(const float4*)&Y2[base + c];
    float4 y3 = *(const float4*)&Y3[base + c];
    v0 += y2.x + y3.x; v1 += y2.y + y3.y; v2 += y2.z + y3.z; v3 += y2.w + y3.w;
  }
  float s = v0+v1+v2+v3;
  float ss = v0*v0+v1*v1+v2*v2+v3*v3;
  for (int off = 32; off; off >>= 1){
    s  += __shfl_down(s, off);
    ss += __shfl_down(ss, off);
  }
  if (lane == 0){ rs[wv] = s; rss[wv] = ss; }
  __syncthreads();
  float S  = rs[0]+rs[1]+rs[2]+rs[3];
  float SS = rss[0]+rss[1]+rss[2]+rss[3];
  float mu = S * (1.f/1024.f);
  float var = SS * (1.f/1024.f) - mu*mu;
  float rinv = rsqrtf(var + LN_EPS);
  float4 gv = *(const float4*)(g + c);
  float4 bb = *(const float4*)(b + c);
  float o0 = (v0-mu)*rinv*gv.x + bb.x;
  float o1 = (v1-mu)*rinv*gv.y + bb.y;
  float o2 = (v2-mu)*rinv*gv.z + bb.z;
  float o3 = (v3-mu)*rinv*gv.w + bb.w;
  *(float4*)&Dst[base + c] = make_float4(o0,o1,o2,o3);
  uint2 ob;
  ob.x = (u32)f2bf(o0) | ((u32)f2bf(o1) << 16);
  ob.y = (u32)f2bf(o2) | ((u32)f2bf(o3) << 16);
  *(uint2*)(DstBf + base + c) = ob;
  if (OutPtr){
    if (*flagp){
      *(uint2*)((u16*)OutPtr + base + c) = ob;
    } else {
      *(float4*)((float*)OutPtr + base + c) = make_float4(o0,o1,o2,o3);
    }
  }
}

extern "C" void kernel_launch(void* const* d_in, const int* in_sizes, int n_in,
                              void* d_out, int out_size, void* d_ws, size_t ws_size,
                              hipStream_t stream)
{
  (void)in_sizes; (void)n_in; (void)out_size; (void)ws_size;

  float* ws   = (float*)d_ws;
  float* R    = ws;                    // 2M f32: x residual / layer input
  float* P0   = R  + 2097152;          // 4x2M contiguous: QKV out, split-K partials
  float* P1   = P0 + 2097152;
  float* P2   = P1 + 2097152;          // v f32
  float* P3   = P2 + 2097152;
  float* KVb  = P3 + 2097152;          // 2M: chunk states, then h (post-LN1) f32
  float* Ks   = KVb + 2097152;         // 32K chunk z
  float* smallP = Ks + 32768;          // 46080 f32 small params
  float* pend = smallP + 46080;
  int* flag = (int*)pend;
  u16* abf  = (u16*)(pend + 4);        // 2M: x / layer-out bf16
  u16* hbf  = abf  + 2097152;          // 2M: post-LN1 bf16
  u16* t1bf = hbf  + 2097152;          // 2M: attn out bf16
  u16* fbf  = t1bf + 2097152;          // 8M: ffn hidden bf16
  u16* qpbf = fbf  + 8388608;          // 2M: Q-phi bf16
  u16* kpbf = qpbf + 2097152;          // 2M: K-phi bf16
  u16* WtQ  = kpbf + 2097152;          // 12M: QKVO transposed, all layers
  u16* WtF1 = WtQ  + 12582912;         // 12M: FFN1 transposed, all layers
  u16* WtF2 = WtF1 + 12582912;         // 12M: FFN2 transposed, all layers

  float* bqF  = smallP + 0;
  float* boF  = smallP + 9216;
  float* omF  = smallP + 12288;
  float* l1gF = smallP + 18432;
  float* l1bF = smallP + 21504;
  float* l2gF = smallP + 24576;
  float* l2bF = smallP + 27648;
  float* bf1F = smallP + 30720;
  float* bf2F = smallP + 43008;

  detect_kernel<<<1, 64, 0, stream>>>((const u16*)d_in[10], flag);
  cvt_small<<<180, 256, 0, stream>>>(d_in[2], d_in[4], d_in[6], d_in[8], d_in[9],
                                     d_in[10], d_in[11], d_in[12], d_in[13],
                                     d_in[15], d_in[17], smallP, flag);
  cvt_x<<<8192, 256, 0, stream>>>(d_in[0], R, abf, 2097152, flag);

  // all weight transposes hoisted out of the layer loop
  transpose_cvtQ<<<dim3(32, 32, 12), 256, 0, stream>>>(d_in[1], d_in[3], d_in[5], d_in[7],
                                                       WtQ, flag);
  transpose_cvtL<<<dim3(128, 32, 3), 256, 0, stream>>>(d_in[14], WtF1, 1024, 4096,
                                                       4194304, 4194304, flag);
  transpose_cvtL<<<dim3(32, 128, 3), 256, 0, stream>>>(d_in[16], WtF2, 4096, 1024,
                                                       4194304, 4194304, flag);

  dim3 gQKV(8, 8, 3);     // 192 blocks (256x128 tiles)
  dim3 gO(8, 8, 2);       // 128 blocks, split-K z=2
  dim3 gF1(32, 8, 1);     // 256 blocks
  dim3 gF2(8, 8, 4);      // 128 blocks, split-K z=4

  for (int l = 0; l < 3; ++l){
    const size_t wQ = (size_t)l * 4194304;

    mfma_gemm8<<<gQKV, 512, 0, stream>>>(abf, WtQ + wQ, bqF + l*1024, P0, (u16*)nullptr,
                                         1024, 1024, 0, 1024,
                                         1048576, 2097152, 3072, 1, 0);
    favor_kernel<<<8192, 256, 0, stream>>>(P0, P1, omF + l*2048, qpbf, kpbf);
    chunk_kv<<<512, 256, 0, stream>>>(P1, P2, KVb, Ks);
    chunk_scan<<<512, 256, 0, stream>>>(KVb, Ks);
    attn_kernel<<<512, 256, 0, stream>>>(qpbf, kpbf, P2, KVb, Ks, t1bf);

    mfma_gemm8<<<gO, 512, 0, stream>>>(t1bf, WtQ + wQ + 3145728, boF + l*1024, P0, (u16*)nullptr,
                                       1024, 1024, 512, 512,
                                       0, 2097152, 0, 0, 0);
    resid_ln<<<2048, 256, 0, stream>>>(R, P0, P1, nullptr, nullptr,
                                       l1gF + l*1024, l1bF + l*1024,
                                       KVb, hbf, nullptr, flag);

    mfma_gemm8<<<gF1, 512, 0, stream>>>(hbf, WtF1 + wQ, bf1F + l*4096, (float*)nullptr, fbf,
                                        4096, 1024, 0, 1024,
                                        0, 0, 0, 1, 1);

    mfma_gemm8<<<gF2, 512, 0, stream>>>(fbf, WtF2 + wQ, bf2F + l*1024, P0, (u16*)nullptr,
                                        1024, 4096, 1024, 1024,
                                        0, 2097152, 0, 0, 0);

    resid_ln<<<2048, 256, 0, stream>>>(KVb, P0, P1, P2, P3,
                                       l2gF + l*1024, l2bF + l*1024,
                                       R, abf, (l == 2) ? d_out : nullptr, flag);
  }
}

// Round 6
// 678.682 us; speedup vs baseline: 1.2630x; 1.0629x over previous
//
#include <hip/hip_runtime.h>

typedef unsigned int u32;
typedef unsigned short u16;
typedef unsigned long long u64;

#define LN_EPS 1e-5f
#define ATTN_EPS 1e-6f

typedef __bf16 bf16x8 __attribute__((ext_vector_type(8)));
typedef short shortx8 __attribute__((ext_vector_type(8)));
typedef float fx4 __attribute__((ext_vector_type(4)));
typedef float fx16 __attribute__((ext_vector_type(16)));

__device__ __forceinline__ u16 f2bf(float f){
  union{float f; u32 u;} x; x.f = f;
  u32 r = 0x7fffu + ((x.u>>16)&1u);
  return (u16)((x.u + r)>>16);
}
__device__ __forceinline__ float bf2f(u16 u){
  union{u32 u; float f;} x; x.u = ((u32)u)<<16; return x.f;
}
__device__ __forceinline__ bf16x8 ldfrag(const u16* p){
  return __builtin_bit_cast(bf16x8, *(const shortx8*)p);
}

// ---------- async global->LDS 16B ----------
__device__ __forceinline__ void async16(const void* g, void* l){
  typedef const __attribute__((address_space(1))) void gas_t;
  typedef __attribute__((address_space(3))) void las_t;
  __builtin_amdgcn_global_load_lds((gas_t*)(u64)g, (las_t*)(u32)(u64)l, 16, 0, 0);
}

// ---------- dtype detect ----------
__global__ void detect_kernel(const u16* __restrict__ ln1g, int* __restrict__ flag){
  if (threadIdx.x == 0 && blockIdx.x == 0)
    *flag = (ln1g[0] == 0x3F80u) ? 1 : 0;
}

// ---------- all small params in one launch ----------
__global__ __launch_bounds__(256) void cvt_small(
    const void* p0, const void* p1, const void* p2, const void* p3,
    const void* p4, const void* p5, const void* p6, const void* p7,
    const void* p8, const void* p9, const void* p10,
    float* __restrict__ out, const int* __restrict__ flagp)
{
  int i = blockIdx.x*256 + threadIdx.x;
  if (i >= 46080) return;
  const void* src; int off;
  if      (i < 3072)  { src=p0;  off=i; }
  else if (i < 6144)  { src=p1;  off=i-3072; }
  else if (i < 9216)  { src=p2;  off=i-6144; }
  else if (i < 12288) { src=p3;  off=i-9216; }
  else if (i < 18432) { src=p4;  off=i-12288; }
  else if (i < 21504) { src=p5;  off=i-18432; }
  else if (i < 24576) { src=p6;  off=i-21504; }
  else if (i < 27648) { src=p7;  off=i-24576; }
  else if (i < 30720) { src=p8;  off=i-27648; }
  else if (i < 43008) { src=p9;  off=i-30720; }
  else                { src=p10; off=i-43008; }
  float v;
  if (*flagp){ union{u32 u; float f;} x; x.u = ((u32)((const u16*)src)[off])<<16; v = x.f; }
  else v = ((const float*)src)[off];
  out[i] = v;
}

// ---------- x convert: f32 + bf16 mirror ----------
__global__ __launch_bounds__(256) void cvt_x(const void* __restrict__ in, float* __restrict__ out,
                                             u16* __restrict__ outbf, int n, const int* __restrict__ flagp){
  int i = blockIdx.x*256 + threadIdx.x;
  if (i >= n) return;
  float v;
  if (*flagp){ union{u32 u; float f;} x; x.u = ((u32)((const u16*)in)[i])<<16; v = x.f; }
  else v = ((const float*)in)[i];
  out[i] = v;
  outbf[i] = f2bf(v);
}

// ---------- weight transpose + convert with layer z: W[K,N] -> Wt[N,K] bf16 ----------
__global__ __launch_bounds__(256) void transpose_cvtL(
    const void* __restrict__ W, u16* __restrict__ Wt,
    int K, int N, size_t zsrc, size_t zdst, const int* __restrict__ flagp)
{
  __shared__ float s[32][33];
  const size_t eoff = (size_t)blockIdx.z * zsrc;
  Wt += (size_t)blockIdx.z * zdst;
  const int bx = blockIdx.x, by = blockIdx.y;
  const int tid = threadIdx.x;
  const int c = tid & 31, r = tid >> 5;
  const int isbf = *flagp;
#pragma unroll
  for (int i = 0; i < 4; ++i){
    int k = by*32 + r + i*8, n = bx*32 + c;
    size_t idx = eoff + (size_t)k*N + n;
    float v;
    if (isbf){ union{u32 u; float f;} x; x.u = ((u32)((const u16*)W)[idx])<<16; v = x.f; }
    else v = ((const float*)W)[idx];
    s[r + i*8][c] = v;
  }
  __syncthreads();
#pragma unroll
  for (int i = 0; i < 4; ++i){
    int n = bx*32 + r + i*8, k = by*32 + c;
    Wt[(size_t)n*K + k] = f2bf(s[c][r + i*8]);
  }
}

// ---------- all 12 QKVO square transposes (3 layers x 4 mats) ----------
__global__ __launch_bounds__(256) void transpose_cvtQ(
    const void* __restrict__ W0, const void* __restrict__ W1,
    const void* __restrict__ W2, const void* __restrict__ W3,
    u16* __restrict__ Wt, const int* __restrict__ flagp)
{
  __shared__ float s[32][33];
  const int z = blockIdx.z, l = z >> 2, m = z & 3;
  const void* W = (m==0)?W0:((m==1)?W1:((m==2)?W2:W3));
  const size_t eoff = (size_t)l * 1048576;
  Wt += (size_t)z * 1048576;
  const int bx = blockIdx.x, by = blockIdx.y;
  const int tid = threadIdx.x;
  const int c = tid & 31, r = tid >> 5;
  const int isbf = *flagp;
#pragma unroll
  for (int i = 0; i < 4; ++i){
    int k = by*32 + r + i*8, n = bx*32 + c;
    size_t idx = eoff + (size_t)k*1024 + n;
    float v;
    if (isbf){ union{u32 u; float f;} x; x.u = ((u32)((const u16*)W)[idx])<<16; v = x.f; }
    else v = ((const float*)W)[idx];
    s[r + i*8][c] = v;
  }
  __syncthreads();
#pragma unroll
  for (int i = 0; i < 4; ++i){
    int n = bx*32 + r + i*8, k = by*32 + c;
    Wt[(size_t)n*1024 + k] = f2bf(s[c][r + i*8]);
  }
}

// ---------- 8-phase-style MFMA GEMM: 256x128 tile, BK=64, TRIPLE buffer ----------
// (R11, kept: measured best GEMM so far; LDS-BW-pinned ceiling for these shapes)
__global__ __launch_bounds__(512, 2) void mfma_gemm8(
    const u16* __restrict__ A, const u16* __restrict__ W,
    const float* __restrict__ bias,
    float* __restrict__ C, u16* __restrict__ Cbf,
    int N, int Kst, int kstep_z, int klen,
    size_t wz, size_t cz, int bz, int bias_all, int relu)
{
  __shared__ u16 As[3][256*64];   // 96 KB
  __shared__ u16 Bs[3][128*64];   // 48 KB
  const int z = blockIdx.z;
  W    += (size_t)z * wz;
  bias += (size_t)z * bz;
  if (C) C += (size_t)z * cz;
  const int kbeg = z * kstep_z;
  const int tid = threadIdx.x;
  const int lane = tid & 63, wid = tid >> 6;
  const size_t KstS = (size_t)Kst;

  // ---- XCD-aware 2D chunk swizzle (8 XCDs as 4x2 grid of chunks) ----
  int bx = blockIdx.x, by = blockIdx.y;
  {
    const int gx = gridDim.x, gy = gridDim.y;
    if (((gx & 3) == 0) && ((gy & 1) == 0)) {
      const int cw = gx >> 2, ch = gy >> 1;
      if (((cw & (cw-1)) == 0) && ((ch & (ch-1)) == 0)) {
        const int o = by*gx + bx;
        const int xcd = o & 7, k = o >> 3;
        const int lgw = 31 - __clz(cw);
        bx = (xcd & 3)*cw + (k & (cw-1));
        by = (xcd >> 2)*ch + (k >> lgw);
      }
    }
  }
  const int row0 = by * 256, col0 = bx * 128;

  const int sR = tid >> 3;
  const int sC = ((tid & 7) ^ (sR & 7)) << 3;
  const u16* gAr = A + (size_t)(row0 + sR)*KstS + kbeg + sC;
  const u16* gBr = W + (size_t)(col0 + sR)*KstS + kbeg + sC;

#define STAGE_H0(b, ks) { const size_t ko = (size_t)(ks) << 6; \
    async16(gAr + ko,                &As[b][tid*8]); \
    async16(gAr + 64*KstS + ko,      &As[b][4096 + tid*8]); \
    async16(gBr + ko,                &Bs[b][tid*8]); }
#define STAGE_H1(b, ks) { const size_t ko = (size_t)(ks) << 6; \
    async16(gAr + 128*KstS + ko,     &As[b][8192 + tid*8]); \
    async16(gAr + 192*KstS + ko,     &As[b][12288 + tid*8]); \
    async16(gBr + 64*KstS + ko,      &Bs[b][4096 + tid*8]); }

  const int nt = klen >> 6;
  STAGE_H0(0, 0) STAGE_H1(0, 0)
  STAGE_H0(1, 1) STAGE_H1(1, 1)
  __builtin_amdgcn_s_waitcnt(0x0F76);   // vmcnt(6)
  __builtin_amdgcn_s_barrier();

  const int l31 = lane & 31, hi = lane >> 5;
  const int wr = (wid >> 1) * 64;
  const int wc = (wid & 1) * 64;
  fx16 acc[2][2] = {};

  for (int t = 0; t < nt; ++t){
    const int buf = t % 3;
    const int nx   = (t + 2 < nt) ? (t + 2) : (nt - 1);
    const int nbuf = (t + 2) % 3;

    bf16x8 a0[2][2], b0[2][2];
#pragma unroll
    for (int kk = 0; kk < 2; ++kk){
      const int sl = ((2*kk + hi) ^ (l31 & 7)) << 3;
#pragma unroll
      for (int mt = 0; mt < 2; ++mt)
        a0[mt][kk] = ldfrag(&As[buf][(wr + mt*32 + l31)*64 + sl]);
#pragma unroll
      for (int ntc = 0; ntc < 2; ++ntc)
        b0[ntc][kk] = ldfrag(&Bs[buf][(wc + ntc*32 + l31)*64 + sl]);
    }
    STAGE_H0(nbuf, nx)
    __builtin_amdgcn_s_barrier();
    __builtin_amdgcn_s_setprio(1);
#pragma unroll
    for (int kk = 0; kk < 2; ++kk)
#pragma unroll
      for (int mt = 0; mt < 2; ++mt)
#pragma unroll
        for (int ntc = 0; ntc < 2; ++ntc)
          acc[mt][ntc] = __builtin_amdgcn_mfma_f32_32x32x16_bf16(a0[mt][kk], b0[ntc][kk], acc[mt][ntc], 0,0,0);
    __builtin_amdgcn_s_setprio(0);
    __builtin_amdgcn_s_barrier();

    bf16x8 a1[2][2], b1[2][2];
#pragma unroll
    for (int kk = 0; kk < 2; ++kk){
      const int sl = ((2*(kk+2) + hi) ^ (l31 & 7)) << 3;
#pragma unroll
      for (int mt = 0; mt < 2; ++mt)
        a1[mt][kk] = ldfrag(&As[buf][(wr + mt*32 + l31)*64 + sl]);
#pragma unroll
      for (int ntc = 0; ntc < 2; ++ntc)
        b1[ntc][kk] = ldfrag(&Bs[buf][(wc + ntc*32 + l31)*64 + sl]);
    }
    STAGE_H1(nbuf, nx)
    __builtin_amdgcn_s_waitcnt(0x0F76);
    __builtin_amdgcn_s_barrier();
    __builtin_amdgcn_s_setprio(1);
#pragma unroll
    for (int kk = 0; kk < 2; ++kk)
#pragma unroll
      for (int mt = 0; mt < 2; ++mt)
#pragma unroll
        for (int ntc = 0; ntc < 2; ++ntc)
          acc[mt][ntc] = __builtin_amdgcn_mfma_f32_32x32x16_bf16(a1[mt][kk], b1[ntc][kk], acc[mt][ntc], 0,0,0);
    __builtin_amdgcn_s_setprio(0);
    __builtin_amdgcn_s_barrier();
  }
  __builtin_amdgcn_s_waitcnt(0x0F70);

  const int rbase = 4*hi;
#pragma unroll
  for (int ntc = 0; ntc < 2; ++ntc){
    const int col = col0 + wc + ntc*32 + l31;
    const float bv = (bias_all || z == 0) ? bias[col] : 0.f;
#pragma unroll
    for (int mt = 0; mt < 2; ++mt){
#pragma unroll
      for (int r = 0; r < 16; ++r){
        const int row = row0 + wr + mt*32 + rbase + (r & 3) + 8*(r >> 2);
        float v = acc[mt][ntc][r] + bv;
        if (relu) v = fmaxf(v, 0.f);
        if (C)   C[(size_t)row*N + col] = v;
        if (Cbf) Cbf[(size_t)row*N + col] = f2bf(v);
      }
    }
  }
#undef STAGE_H0
#undef STAGE_H1
}

// ---------- FUSED: favor(K) + per-chunk KVt + Ksum ----------
// R12: computes phi-K in-LDS from raw K (kills favor_kernel's K half + the
// f32 phi round-trip), writes Kb bf16 mirror for attn, then the usual
// KVt[d][m] = sum_j phiK[j][m] V[j][d] and Ksum = sum_j phiK[j].
__global__ __launch_bounds__(256) void chunk_kv_favor(
    const float* __restrict__ Kraw, const float* __restrict__ V,
    const float* __restrict__ omega,
    float* __restrict__ KV, float* __restrict__ Ksum, u16* __restrict__ Kb)
{
  __shared__ float Xs[64][68];   // scaled raw K (pad 68: 2-way banks on dot reads)
  __shared__ float Vs[64][64];
  __shared__ float Ph[64][68];   // phi-K f32
  __shared__ float Om[64][32];
  const int blk = blockIdx.x;
  const int c = blk & 15, h = (blk >> 4) & 15, b = blk >> 8;
  const int tid = threadIdx.x;
  const int t0 = b*1024 + c*64;

  for (int i = tid; i < 2048; i += 256)
    Om[i>>5][i&31] = omega[i];
  for (int i = tid; i < 1024; i += 256){
    int j = i >> 4, m4 = (i & 15) << 2;
    size_t src = (size_t)(t0 + j)*1024 + h*64 + m4;
    float4 kv4 = *(const float4*)&Kraw[src];
    float4 xs4 = make_float4(kv4.x*0.35355339059327373f, kv4.y*0.35355339059327373f,
                             kv4.z*0.35355339059327373f, kv4.w*0.35355339059327373f);
    *(float4*)&Xs[j][m4] = xs4;                 // row stride 68 f32 = 272B, 16B-aligned
    *(float4*)&Vs[j][m4] = *(const float4*)&V[src];
  }
  __syncthreads();

  // ---- phi: thread (tok = tid>>2, q = tid&3) computes 8 u-dots -> 16 phi ----
  {
    const int tok = tid >> 2, q = tid & 3;
    float u[8] = {0,0,0,0,0,0,0,0};
    float hh = 0.f;
    for (int d = 0; d < 64; ++d){
      float xv = Xs[tok][d];
      hh = fmaf(xv, xv, hh);
      float4 o0 = *(const float4*)&Om[d][q*8];
      float4 o1 = *(const float4*)&Om[d][q*8+4];
      u[0]=fmaf(xv,o0.x,u[0]); u[1]=fmaf(xv,o0.y,u[1]);
      u[2]=fmaf(xv,o0.z,u[2]); u[3]=fmaf(xv,o0.w,u[3]);
      u[4]=fmaf(xv,o1.x,u[4]); u[5]=fmaf(xv,o1.y,u[5]);
      u[6]=fmaf(xv,o1.z,u[6]); u[7]=fmaf(xv,o1.w,u[7]);
    }
    hh *= 0.5f;
#pragma unroll
    for (int i = 0; i < 8; ++i){
      Ph[tok][q*8+i]    = expf( u[i] - hh) * 0.125f;
      Ph[tok][32+q*8+i] = expf(-u[i] - hh) * 0.125f;
    }
  }
  __syncthreads();

  // ---- Kb bf16 mirror (coalesced) ----
  {
    const int r = tid >> 2, c4 = (tid & 3) << 4;
    u16 tmp[16];
#pragma unroll
    for (int j = 0; j < 16; ++j) tmp[j] = f2bf(Ph[r][c4 + j]);
    size_t g = (size_t)(t0 + r)*1024 + h*64 + c4;
    *(uint4*)(Kb + g)     = *(uint4*)&tmp[0];
    *(uint4*)(Kb + g + 8) = *(uint4*)&tmp[8];
  }

  // ---- KVt + Ksum from in-LDS phi ----
  const int m = tid & 63, dg = tid >> 6;
  float acc[16] = {0.f};
  for (int j = 0; j < 64; ++j){
    float kv = Ph[j][m];
#pragma unroll
    for (int di = 0; di < 16; ++di)
      acc[di] = fmaf(Vs[j][dg*16+di], kv, acc[di]);
  }
  size_t outb = (size_t)blk * 4096;
#pragma unroll
  for (int di = 0; di < 16; ++di)
    KV[outb + (size_t)(dg*16+di)*64 + m] = acc[di];
  if (tid < 64){
    float s = 0.f;
    for (int j = 0; j < 64; ++j) s += Ph[j][tid];
    Ksum[(size_t)blk*64 + tid] = s;
  }
}

// ---------- exclusive prefix over chunks (elementwise; layout-agnostic) ----------
__global__ __launch_bounds__(256) void chunk_scan(float* __restrict__ KV, float* __restrict__ Ksum)
{
  int blk = blockIdx.x;
  int bh = blk >> 4, ec = blk & 15;
  int e = ec*256 + threadIdx.x;
  size_t base = (size_t)bh * 65536 + e;
  float run = 0.f;
  for (int c = 0; c < 16; ++c){
    size_t idx = base + (size_t)c*4096;
    float t = KV[idx]; KV[idx] = run; run += t;
  }
  if (ec == 0 && threadIdx.x < 64){
    size_t kb = (size_t)bh * 1024 + threadIdx.x;
    float rz = 0.f;
    for (int c = 0; c < 16; ++c){
      size_t idx = kb + c*64;
      float t = Ksum[idx]; Ksum[idx] = rz; rz += t;
    }
  }
}

// ---------- MFMA intra-chunk causal attention, FUSED favor(Q) ----------
// R12: reads raw Q (f32) + omega, computes phi-Q in-LDS into Qs (bf16) after
// the V->Vt transpose frees Vrow. Math identical to the old favor_kernel.
__global__ __launch_bounds__(256) void attn_kernel(
    const float* __restrict__ Qraw, const u16* __restrict__ Kbf,
    const float* __restrict__ V, const float* __restrict__ KVt,
    const float* __restrict__ Ksum, const float* __restrict__ omega,
    u16* __restrict__ Outbf)
{
  __shared__ u16 Qs[64][72];
  __shared__ u16 Ks[64][72];
  __shared__ u16 Ss[64][72];
  __shared__ u16 Vt[64][72];
  __shared__ u16 Pt[64][72];
  __shared__ float Vrow[64][68];   // V rows, then reused as scaled raw Q
  __shared__ float Om[64][32];
  __shared__ float densum[64];

  const int blk = blockIdx.x;
  const int c = blk & 15, h = (blk >> 4) & 15, b = blk >> 8;
  const int tid = threadIdx.x;
  const int lane = tid & 63, w = tid >> 6;
  const int quad = lane >> 4, l16 = lane & 15;
  const int t0 = b*1024 + c*64;
  const int r = tid >> 2, q4 = (tid & 3) << 4;
  const size_t g = (size_t)(t0 + r)*1024 + h*64 + q4;

  for (int i = tid; i < 2048; i += 256)
    Om[i>>5][i&31] = omega[i];
  {
    *(uint4*)&Ks[r][q4]   = *(const uint4*)(Kbf + g);
    *(uint4*)&Ks[r][q4+8] = *(const uint4*)(Kbf + g + 8);
    const float* vg = V + g;
    *(float4*)&Vrow[r][q4+0]  = *(const float4*)(vg+0);
    *(float4*)&Vrow[r][q4+4]  = *(const float4*)(vg+4);
    *(float4*)&Vrow[r][q4+8]  = *(const float4*)(vg+8);
    *(float4*)&Vrow[r][q4+12] = *(const float4*)(vg+12);
    const float* pg = KVt + (size_t)blk*4096 + r*64 + q4;
    u16 tmp[16];
#pragma unroll
    for (int j = 0; j < 16; ++j) tmp[j] = f2bf(pg[j]);
    *(uint4*)&Pt[r][q4]   = *(uint4*)&tmp[0];
    *(uint4*)&Pt[r][q4+8] = *(uint4*)&tmp[8];
  }
  __syncthreads();
  // ---- transpose Vrow -> Vt bf16 [d][j] ----
  {
    const int d = tid >> 2, j16 = (tid & 3) << 4;
    u16 tmp[16];
#pragma unroll
    for (int j = 0; j < 16; ++j) tmp[j] = f2bf(Vrow[j16+j][d]);
    *(uint4*)&Vt[d][j16]   = *(uint4*)&tmp[0];
    *(uint4*)&Vt[d][j16+8] = *(uint4*)&tmp[8];
  }
  __syncthreads();
  // ---- restage Vrow <- scaled raw Q ----
  {
    const float* qg = Qraw + g;
    float4 a0 = *(const float4*)(qg+0), a1 = *(const float4*)(qg+4);
    float4 a2 = *(const float4*)(qg+8), a3 = *(const float4*)(qg+12);
    const float sc = 0.35355339059327373f;
    *(float4*)&Vrow[r][q4+0]  = make_float4(a0.x*sc, a0.y*sc, a0.z*sc, a0.w*sc);
    *(float4*)&Vrow[r][q4+4]  = make_float4(a1.x*sc, a1.y*sc, a1.z*sc, a1.w*sc);
    *(float4*)&Vrow[r][q4+8]  = make_float4(a2.x*sc, a2.y*sc, a2.z*sc, a2.w*sc);
    *(float4*)&Vrow[r][q4+12] = make_float4(a3.x*sc, a3.y*sc, a3.z*sc, a3.w*sc);
  }
  __syncthreads();
  // ---- phi-Q -> Qs bf16 (pairs) ----
  {
    const int tok = tid >> 2, q = tid & 3;
    float u[8] = {0,0,0,0,0,0,0,0};
    float hh = 0.f;
    for (int d = 0; d < 64; ++d){
      float xv = Vrow[tok][d];
      hh = fmaf(xv, xv, hh);
      float4 o0 = *(const float4*)&Om[d][q*8];
      float4 o1 = *(const float4*)&Om[d][q*8+4];
      u[0]=fmaf(xv,o0.x,u[0]); u[1]=fmaf(xv,o0.y,u[1]);
      u[2]=fmaf(xv,o0.z,u[2]); u[3]=fmaf(xv,o0.w,u[3]);
      u[4]=fmaf(xv,o1.x,u[4]); u[5]=fmaf(xv,o1.y,u[5]);
      u[6]=fmaf(xv,o1.z,u[6]); u[7]=fmaf(xv,o1.w,u[7]);
    }
    hh *= 0.5f;
#pragma unroll
    for (int i = 0; i < 8; i += 2){
      float e0 = expf( u[i]   - hh) * 0.125f;
      float e1 = expf( u[i+1] - hh) * 0.125f;
      *(u32*)&Qs[tok][q*8+i]    = (u32)f2bf(e0) | ((u32)f2bf(e1) << 16);
      float f0 = expf(-u[i]   - hh) * 0.125f;
      float f1 = expf(-u[i+1] - hh) * 0.125f;
      *(u32*)&Qs[tok][32+q*8+i] = (u32)f2bf(f0) | ((u32)f2bf(f1) << 16);
    }
  }
  __syncthreads();

  // ---- phase 1: S = Q K^T ----
  const int iw0 = w*16;
  bf16x8 aq0 = ldfrag(&Qs[iw0+l16][quad*8]);
  bf16x8 aq1 = ldfrag(&Qs[iw0+l16][32+quad*8]);
  fx4 sacc[4];
#pragma unroll
  for (int u = 0; u < 4; ++u){
    sacc[u] = (fx4){0.f,0.f,0.f,0.f};
    bf16x8 b0 = ldfrag(&Ks[u*16+l16][quad*8]);
    bf16x8 b1 = ldfrag(&Ks[u*16+l16][32+quad*8]);
    sacc[u] = __builtin_amdgcn_mfma_f32_16x16x32_bf16(aq0, b0, sacc[u], 0, 0, 0);
    sacc[u] = __builtin_amdgcn_mfma_f32_16x16x32_bf16(aq1, b1, sacc[u], 0, 0, 0);
  }
  float rs[4] = {0.f,0.f,0.f,0.f};
#pragma unroll
  for (int u = 0; u < 4; ++u){
    const int jl = u*16 + l16;
#pragma unroll
    for (int rr = 0; rr < 4; ++rr){
      const int il = iw0 + quad*4 + rr;
      float v = (jl <= il) ? sacc[u][rr] : 0.f;
      rs[rr] += v;
      Ss[il][jl] = f2bf(v);
    }
  }
#pragma unroll
  for (int off = 1; off < 16; off <<= 1){
#pragma unroll
    for (int rr = 0; rr < 4; ++rr) rs[rr] += __shfl_xor(rs[rr], off);
  }
  if (l16 == 0){
#pragma unroll
    for (int rr = 0; rr < 4; ++rr) densum[iw0 + quad*4 + rr] = rs[rr];
  }
  __syncthreads();

  {
    const int row = iw0 + l16;
    const float* zp = Ksum + (size_t)blk*64;
    float dp = 0.f;
#pragma unroll
    for (int m = 0; m < 16; ++m){
      const int mm = quad*16 + m;
      dp = fmaf(bf2f(Qs[row][mm]), zp[mm], dp);
    }
    dp += __shfl_xor(dp, 16);
    dp += __shfl_xor(dp, 32);
    if (quad == 0) densum[row] = densum[row] + dp + ATTN_EPS;
  }
  __syncthreads();

  bf16x8 as0 = ldfrag(&Ss[iw0+l16][quad*8]);
  bf16x8 as1 = ldfrag(&Ss[iw0+l16][32+quad*8]);
  fx4 oacc[4];
#pragma unroll
  for (int u = 0; u < 4; ++u){
    const int d0 = u*16;
    oacc[u] = (fx4){0.f,0.f,0.f,0.f};
    oacc[u] = __builtin_amdgcn_mfma_f32_16x16x32_bf16(as0, ldfrag(&Vt[d0+l16][quad*8]),    oacc[u], 0,0,0);
    oacc[u] = __builtin_amdgcn_mfma_f32_16x16x32_bf16(as1, ldfrag(&Vt[d0+l16][32+quad*8]), oacc[u], 0,0,0);
    oacc[u] = __builtin_amdgcn_mfma_f32_16x16x32_bf16(aq0, ldfrag(&Pt[d0+l16][quad*8]),    oacc[u], 0,0,0);
    oacc[u] = __builtin_amdgcn_mfma_f32_16x16x32_bf16(aq1, ldfrag(&Pt[d0+l16][32+quad*8]), oacc[u], 0,0,0);
  }
#pragma unroll
  for (int u = 0; u < 4; ++u){
    const int d = u*16 + l16;
#pragma unroll
    for (int rr = 0; rr < 4; ++rr){
      const int il = iw0 + quad*4 + rr;
      const float o = oacc[u][rr] / densum[il];
      Outbf[(size_t)(t0 + il)*1024 + h*64 + d] = f2bf(o);
    }
  }
}

// ---------- residual + LayerNorm: ln(X + Y0 + Y1 [+ Y2 + Y3]) ----------
__global__ __launch_bounds__(256) void resid_ln(
    const float* __restrict__ X, const float* __restrict__ Y0, const float* __restrict__ Y1,
    const float* __restrict__ Y2, const float* __restrict__ Y3,
    const float* __restrict__ g, const float* __restrict__ b,
    float* __restrict__ Dst, u16* __restrict__ DstBf,
    void* __restrict__ OutPtr, const int* __restrict__ flagp)
{
  __shared__ float rs[4], rss[4];
  int row = blockIdx.x, tid = threadIdx.x;
  int lane = tid & 63, wv = tid >> 6;
  size_t base = (size_t)row * 1024;
  int c = tid << 2;
  float4 xv = *(const float4*)&X[base + c];
  float4 y0 = *(const float4*)&Y0[base + c];
  float4 y1 = *(const float4*)&Y1[base + c];
  float v0 = xv.x+y0.x+y1.x, v1 = xv.y+y0.y+y1.y, v2 = xv.z+y0.z+y1.z, v3 = xv.w+y0.w+y1.w;
  if (Y2){
    float4 y2 = *(const float4*)&Y2[base + c];
    float4 y3 = *(const float4*)&Y3[base + c];
    v0 += y2.x + y3.x; v1 += y2.y + y3.y; v2 += y2.z + y3.z; v3 += y2.w + y3.w;
  }
  float s = v0+v1+v2+v3;
  float ss = v0*v0+v1*v1+v2*v2+v3*v3;
  for (int off = 32; off; off >>= 1){
    s  += __shfl_down(s, off);
    ss += __shfl_down(ss, off);
  }
  if (lane == 0){ rs[wv] = s; rss[wv] = ss; }
  __syncthreads();
  float S  = rs[0]+rs[1]+rs[2]+rs[3];
  float SS = rss[0]+rss[1]+rss[2]+rss[3];
  float mu = S * (1.f/1024.f);
  float var = SS * (1.f/1024.f) - mu*mu;
  float rinv = rsqrtf(var + LN_EPS);
  float4 gv = *(const float4*)(g + c);
  float4 bb = *(const float4*)(b + c);
  float o0 = (v0-mu)*rinv*gv.x + bb.x;
  float o1 = (v1-mu)*rinv*gv.y + bb.y;
  float o2 = (v2-mu)*rinv*gv.z + bb.z;
  float o3 = (v3-mu)*rinv*gv.w + bb.w;
  *(float4*)&Dst[base + c] = make_float4(o0,o1,o2,o3);
  uint2 ob;
  ob.x = (u32)f2bf(o0) | ((u32)f2bf(o1) << 16);
  ob.y = (u32)f2bf(o2) | ((u32)f2bf(o3) << 16);
  *(uint2*)(DstBf + base + c) = ob;
  if (OutPtr){
    if (*flagp){
      *(uint2*)((u16*)OutPtr + base + c) = ob;
    } else {
      *(float4*)((float*)OutPtr + base + c) = make_float4(o0,o1,o2,o3);
    }
  }
}

extern "C" void kernel_launch(void* const* d_in, const int* in_sizes, int n_in,
                              void* d_out, int out_size, void* d_ws, size_t ws_size,
                              hipStream_t stream)
{
  (void)in_sizes; (void)n_in; (void)out_size; (void)ws_size;

  float* ws   = (float*)d_ws;
  float* R    = ws;                    // 2M f32: x residual / layer input
  float* P0   = R  + 2097152;          // 4x2M contiguous: QKV out, split-K partials
  float* P1   = P0 + 2097152;
  float* P2   = P1 + 2097152;          // v f32
  float* P3   = P2 + 2097152;
  float* KVb  = P3 + 2097152;          // 2M: chunk states, then h (post-LN1) f32
  float* Ks   = KVb + 2097152;         // 32K chunk z
  float* smallP = Ks + 32768;          // 46080 f32 small params
  float* pend = smallP + 46080;
  int* flag = (int*)pend;
  u16* abf  = (u16*)(pend + 4);        // 2M: x / layer-out bf16
  u16* hbf  = abf  + 2097152;          // 2M: post-LN1 bf16
  u16* t1bf = hbf  + 2097152;          // 2M: attn out bf16
  u16* fbf  = t1bf + 2097152;          // 8M: ffn hidden bf16
  u16* kpbf = fbf  + 8388608;          // 2M: K-phi bf16
  u16* WtQ  = kpbf + 2097152;          // 12M: QKVO transposed, all layers
  u16* WtF1 = WtQ  + 12582912;         // 12M: FFN1 transposed, all layers
  u16* WtF2 = WtF1 + 12582912;         // 12M: FFN2 transposed, all layers

  float* bqF  = smallP + 0;
  float* boF  = smallP + 9216;
  float* omF  = smallP + 12288;
  float* l1gF = smallP + 18432;
  float* l1bF = smallP + 21504;
  float* l2gF = smallP + 24576;
  float* l2bF = smallP + 27648;
  float* bf1F = smallP + 30720;
  float* bf2F = smallP + 43008;

  detect_kernel<<<1, 64, 0, stream>>>((const u16*)d_in[10], flag);
  cvt_small<<<180, 256, 0, stream>>>(d_in[2], d_in[4], d_in[6], d_in[8], d_in[9],
                                     d_in[10], d_in[11], d_in[12], d_in[13],
                                     d_in[15], d_in[17], smallP, flag);
  cvt_x<<<8192, 256, 0, stream>>>(d_in[0], R, abf, 2097152, flag);

  // all weight transposes hoisted out of the layer loop
  transpose_cvtQ<<<dim3(32, 32, 12), 256, 0, stream>>>(d_in[1], d_in[3], d_in[5], d_in[7],
                                                       WtQ, flag);
  transpose_cvtL<<<dim3(128, 32, 3), 256, 0, stream>>>(d_in[14], WtF1, 1024, 4096,
                                                       4194304, 4194304, flag);
  transpose_cvtL<<<dim3(32, 128, 3), 256, 0, stream>>>(d_in[16], WtF2, 4096, 1024,
                                                       4194304, 4194304, flag);

  dim3 gQKV(8, 8, 3);     // 192 blocks (256x128 tiles)
  dim3 gO(8, 8, 2);       // 128 blocks, split-K z=2
  dim3 gF1(32, 8, 1);     // 256 blocks
  dim3 gF2(8, 8, 4);      // 128 blocks, split-K z=4

  for (int l = 0; l < 3; ++l){
    const size_t wQ = (size_t)l * 4194304;

    mfma_gemm8<<<gQKV, 512, 0, stream>>>(abf, WtQ + wQ, bqF + l*1024, P0, (u16*)nullptr,
                                         1024, 1024, 0, 1024,
                                         1048576, 2097152, 3072, 1, 0);
    chunk_kv_favor<<<512, 256, 0, stream>>>(P1, P2, omF + l*2048, KVb, Ks, kpbf);
    chunk_scan<<<512, 256, 0, stream>>>(KVb, Ks);
    attn_kernel<<<512, 256, 0, stream>>>(P0, kpbf, P2, KVb, Ks, omF + l*2048, t1bf);

    mfma_gemm8<<<gO, 512, 0, stream>>>(t1bf, WtQ + wQ + 3145728, boF + l*1024, P0, (u16*)nullptr,
                                       1024, 1024, 512, 512,
                                       0, 2097152, 0, 0, 0);
    resid_ln<<<2048, 256, 0, stream>>>(R, P0, P1, nullptr, nullptr,
                                       l1gF + l*1024, l1bF + l*1024,
                                       KVb, hbf, nullptr, flag);

    mfma_gemm8<<<gF1, 512, 0, stream>>>(hbf, WtF1 + wQ, bf1F + l*4096, (float*)nullptr, fbf,
                                        4096, 1024, 0, 1024,
                                        0, 0, 0, 1, 1);

    mfma_gemm8<<<gF2, 512, 0, stream>>>(fbf, WtF2 + wQ, bf2F + l*1024, P0, (u16*)nullptr,
                                        1024, 4096, 1024, 1024,
                                        0, 2097152, 0, 0, 0);

    resid_ln<<<2048, 256, 0, stream>>>(KVb, P0, P1, P2, P3,
                                       l2gF + l*1024, l2bF + l*1024,
                                       R, abf, (l == 2) ? d_out : nullptr, flag);
  }
}

// Round 7
// 668.974 us; speedup vs baseline: 1.2814x; 1.0145x over previous
//
#include <hip/hip_runtime.h>

typedef unsigned int u32;
typedef unsigned short u16;
typedef unsigned long long u64;

#define LN_EPS 1e-5f
#define ATTN_EPS 1e-6f

typedef __bf16 bf16x8 __attribute__((ext_vector_type(8)));
typedef short shortx8 __attribute__((ext_vector_type(8)));
typedef float fx4 __attribute__((ext_vector_type(4)));
typedef float fx16 __attribute__((ext_vector_type(16)));

__device__ __forceinline__ u16 f2bf(float f){
  union{float f; u32 u;} x; x.f = f;
  u32 r = 0x7fffu + ((x.u>>16)&1u);
  return (u16)((x.u + r)>>16);
}
__device__ __forceinline__ float bf2f(u16 u){
  union{u32 u; float f;} x; x.u = ((u32)u)<<16; return x.f;
}
__device__ __forceinline__ bf16x8 ldfrag(const u16* p){
  return __builtin_bit_cast(bf16x8, *(const shortx8*)p);
}

// ---------- async global->LDS 16B ----------
__device__ __forceinline__ void async16(const void* g, void* l){
  typedef const __attribute__((address_space(1))) void gas_t;
  typedef __attribute__((address_space(3))) void las_t;
  __builtin_amdgcn_global_load_lds((gas_t*)(u64)g, (las_t*)(u32)(u64)l, 16, 0, 0);
}

// ---------- dtype detect ----------
__global__ void detect_kernel(const u16* __restrict__ ln1g, int* __restrict__ flag){
  if (threadIdx.x == 0 && blockIdx.x == 0)
    *flag = (ln1g[0] == 0x3F80u) ? 1 : 0;
}

// ---------- all small params in one launch ----------
__global__ __launch_bounds__(256) void cvt_small(
    const void* p0, const void* p1, const void* p2, const void* p3,
    const void* p4, const void* p5, const void* p6, const void* p7,
    const void* p8, const void* p9, const void* p10,
    float* __restrict__ out, const int* __restrict__ flagp)
{
  int i = blockIdx.x*256 + threadIdx.x;
  if (i >= 46080) return;
  const void* src; int off;
  if      (i < 3072)  { src=p0;  off=i; }
  else if (i < 6144)  { src=p1;  off=i-3072; }
  else if (i < 9216)  { src=p2;  off=i-6144; }
  else if (i < 12288) { src=p3;  off=i-9216; }
  else if (i < 18432) { src=p4;  off=i-12288; }
  else if (i < 21504) { src=p5;  off=i-18432; }
  else if (i < 24576) { src=p6;  off=i-21504; }
  else if (i < 27648) { src=p7;  off=i-24576; }
  else if (i < 30720) { src=p8;  off=i-27648; }
  else if (i < 43008) { src=p9;  off=i-30720; }
  else                { src=p10; off=i-43008; }
  float v;
  if (*flagp){ union{u32 u; float f;} x; x.u = ((u32)((const u16*)src)[off])<<16; v = x.f; }
  else v = ((const float*)src)[off];
  out[i] = v;
}

// ---------- x convert: f32 + bf16 mirror ----------
__global__ __launch_bounds__(256) void cvt_x(const void* __restrict__ in, float* __restrict__ out,
                                             u16* __restrict__ outbf, int n, const int* __restrict__ flagp){
  int i = blockIdx.x*256 + threadIdx.x;
  if (i >= n) return;
  float v;
  if (*flagp){ union{u32 u; float f;} x; x.u = ((u32)((const u16*)in)[i])<<16; v = x.f; }
  else v = ((const float*)in)[i];
  out[i] = v;
  outbf[i] = f2bf(v);
}

// ---------- weight transpose + convert with layer z: W[K,N] -> Wt[N,K] bf16 ----------
__global__ __launch_bounds__(256) void transpose_cvtL(
    const void* __restrict__ W, u16* __restrict__ Wt,
    int K, int N, size_t zsrc, size_t zdst, const int* __restrict__ flagp)
{
  __shared__ float s[32][33];
  const size_t eoff = (size_t)blockIdx.z * zsrc;
  Wt += (size_t)blockIdx.z * zdst;
  const int bx = blockIdx.x, by = blockIdx.y;
  const int tid = threadIdx.x;
  const int c = tid & 31, r = tid >> 5;
  const int isbf = *flagp;
#pragma unroll
  for (int i = 0; i < 4; ++i){
    int k = by*32 + r + i*8, n = bx*32 + c;
    size_t idx = eoff + (size_t)k*N + n;
    float v;
    if (isbf){ union{u32 u; float f;} x; x.u = ((u32)((const u16*)W)[idx])<<16; v = x.f; }
    else v = ((const float*)W)[idx];
    s[r + i*8][c] = v;
  }
  __syncthreads();
#pragma unroll
  for (int i = 0; i < 4; ++i){
    int n = bx*32 + r + i*8, k = by*32 + c;
    Wt[(size_t)n*K + k] = f2bf(s[c][r + i*8]);
  }
}

// ---------- all 12 QKVO square transposes (3 layers x 4 mats) ----------
__global__ __launch_bounds__(256) void transpose_cvtQ(
    const void* __restrict__ W0, const void* __restrict__ W1,
    const void* __restrict__ W2, const void* __restrict__ W3,
    u16* __restrict__ Wt, const int* __restrict__ flagp)
{
  __shared__ float s[32][33];
  const int z = blockIdx.z, l = z >> 2, m = z & 3;
  const void* W = (m==0)?W0:((m==1)?W1:((m==2)?W2:W3));
  const size_t eoff = (size_t)l * 1048576;
  Wt += (size_t)z * 1048576;
  const int bx = blockIdx.x, by = blockIdx.y;
  const int tid = threadIdx.x;
  const int c = tid & 31, r = tid >> 5;
  const int isbf = *flagp;
#pragma unroll
  for (int i = 0; i < 4; ++i){
    int k = by*32 + r + i*8, n = bx*32 + c;
    size_t idx = eoff + (size_t)k*1024 + n;
    float v;
    if (isbf){ union{u32 u; float f;} x; x.u = ((u32)((const u16*)W)[idx])<<16; v = x.f; }
    else v = ((const float*)W)[idx];
    s[r + i*8][c] = v;
  }
  __syncthreads();
#pragma unroll
  for (int i = 0; i < 4; ++i){
    int n = bx*32 + r + i*8, k = by*32 + c;
    Wt[(size_t)n*1024 + k] = f2bf(s[c][r + i*8]);
  }
}

// ---------- MFMA GEMM: 256x128 tile, BK=64, TRIPLE buffer, ONE barrier/K-step ----------
// R13: the R11 4-barriers-per-K-step schedule collapses to one.
// Hazard ledger (triple buffer):
//   * step t reads buf t%3 (frags -> registers BEFORE the step's barrier);
//   * step t stages into (t+2)%3 == (t-1)%3, whose readers all finished before
//     the end-of-(t-1) barrier -> write-after-read safe;
//   * cross-wave visibility of step t+1's staged data: vmcnt(6) (retires t+1's
//     6 loads per-wave; t+2's 6 stay IN FLIGHT, T4) + single s_barrier.
// MFMA consumes registers, so no LDS read crosses the barrier.
__global__ __launch_bounds__(512, 2) void mfma_gemm8(
    const u16* __restrict__ A, const u16* __restrict__ W,
    const float* __restrict__ bias,
    float* __restrict__ C, u16* __restrict__ Cbf,
    int N, int Kst, int kstep_z, int klen,
    size_t wz, size_t cz, int bz, int bias_all, int relu)
{
  __shared__ u16 As[3][256*64];   // 96 KB
  __shared__ u16 Bs[3][128*64];   // 48 KB
  const int z = blockIdx.z;
  W    += (size_t)z * wz;
  bias += (size_t)z * bz;
  if (C) C += (size_t)z * cz;
  const int kbeg = z * kstep_z;
  const int tid = threadIdx.x;
  const int lane = tid & 63, wid = tid >> 6;
  const size_t KstS = (size_t)Kst;

  // ---- XCD-aware 2D chunk swizzle (8 XCDs as 4x2 grid of chunks) ----
  int bx = blockIdx.x, by = blockIdx.y;
  {
    const int gx = gridDim.x, gy = gridDim.y;
    if (((gx & 3) == 0) && ((gy & 1) == 0)) {
      const int cw = gx >> 2, ch = gy >> 1;
      if (((cw & (cw-1)) == 0) && ((ch & (ch-1)) == 0)) {
        const int o = by*gx + bx;
        const int xcd = o & 7, k = o >> 3;
        const int lgw = 31 - __clz(cw);
        bx = (xcd & 3)*cw + (k & (cw-1));
        by = (xcd >> 2)*ch + (k >> lgw);
      }
    }
  }
  const int row0 = by * 256, col0 = bx * 128;

  // staging: linear LDS dest + inverse-swizzled global source (rule 21):
  // slot s of row r holds global k-chunk s ^ (r&7).
  const int sR = tid >> 3;
  const int sC = ((tid & 7) ^ (sR & 7)) << 3;
  const u16* gAr = A + (size_t)(row0 + sR)*KstS + kbeg + sC;
  const u16* gBr = W + (size_t)(col0 + sR)*KstS + kbeg + sC;

#define STAGE_ALL(b, ks) { const size_t ko = (size_t)(ks) << 6; \
    async16(gAr + ko,                &As[b][tid*8]); \
    async16(gAr + 64*KstS + ko,      &As[b][4096 + tid*8]); \
    async16(gAr + 128*KstS + ko,     &As[b][8192 + tid*8]); \
    async16(gAr + 192*KstS + ko,     &As[b][12288 + tid*8]); \
    async16(gBr + ko,                &Bs[b][tid*8]); \
    async16(gBr + 64*KstS + ko,      &Bs[b][4096 + tid*8]); }

  const int nt = klen >> 6;
  STAGE_ALL(0, 0)
  STAGE_ALL(1, 1)
  __builtin_amdgcn_s_waitcnt(0x0F76);   // vmcnt(6): step 0 landed, step 1 in flight
  __builtin_amdgcn_s_barrier();

  const int l31 = lane & 31, hi = lane >> 5;
  const int wr = (wid >> 1) * 64;
  const int wc = (wid & 1) * 64;
  fx16 acc[2][2] = {};

  for (int t = 0; t < nt; ++t){
    const int buf = t % 3;
    const int nx   = (t + 2 < nt) ? (t + 2) : (nt - 1);   // tail: dead-buffer writes
    const int nbuf = (t + 2) % 3;

    // all frags for this K-step (kh = 0..3), swizzled slots
    bf16x8 af[4][2], bg[4][2];          // [kh][mt/ntc]
#pragma unroll
    for (int kh = 0; kh < 4; ++kh){
      const int sl = ((2*kh + hi) ^ (l31 & 7)) << 3;
#pragma unroll
      for (int mt = 0; mt < 2; ++mt)
        af[kh][mt] = ldfrag(&As[buf][(wr + mt*32 + l31)*64 + sl]);
#pragma unroll
      for (int ntc = 0; ntc < 2; ++ntc)
        bg[kh][ntc] = ldfrag(&Bs[buf][(wc + ntc*32 + l31)*64 + sl]);
    }
    STAGE_ALL(nbuf, nx)
    __builtin_amdgcn_s_setprio(1);
#pragma unroll
    for (int kh = 0; kh < 4; ++kh)
#pragma unroll
      for (int mt = 0; mt < 2; ++mt)
#pragma unroll
        for (int ntc = 0; ntc < 2; ++ntc)
          acc[mt][ntc] = __builtin_amdgcn_mfma_f32_32x32x16_bf16(af[kh][mt], bg[kh][ntc], acc[mt][ntc], 0,0,0);
    __builtin_amdgcn_s_setprio(0);
    __builtin_amdgcn_s_waitcnt(0x0F76); // vmcnt(6): t+1 landed, t+2 in flight (T4)
    __builtin_amdgcn_s_barrier();       // the ONLY barrier per K-step
  }
  __builtin_amdgcn_s_waitcnt(0x0F70);   // drain tail staging

  // C/D layout (32x32): col = lane&31, row = (r&3) + 8*(r>>2) + 4*(lane>>5)
  const int rbase = 4*hi;
#pragma unroll
  for (int ntc = 0; ntc < 2; ++ntc){
    const int col = col0 + wc + ntc*32 + l31;
    const float bv = (bias_all || z == 0) ? bias[col] : 0.f;
#pragma unroll
    for (int mt = 0; mt < 2; ++mt){
#pragma unroll
      for (int r = 0; r < 16; ++r){
        const int row = row0 + wr + mt*32 + rbase + (r & 3) + 8*(r >> 2);
        float v = acc[mt][ntc][r] + bv;
        if (relu) v = fmaxf(v, 0.f);
        if (C)   C[(size_t)row*N + col] = v;
        if (Cbf) Cbf[(size_t)row*N + col] = f2bf(v);
      }
    }
  }
#undef STAGE_ALL
}

// ---------- FUSED: favor(K) + per-chunk KVt + Ksum ----------
__global__ __launch_bounds__(256) void chunk_kv_favor(
    const float* __restrict__ Kraw, const float* __restrict__ V,
    const float* __restrict__ omega,
    float* __restrict__ KV, float* __restrict__ Ksum, u16* __restrict__ Kb)
{
  __shared__ float Xs[64][68];
  __shared__ float Vs[64][64];
  __shared__ float Ph[64][68];
  __shared__ float Om[64][32];
  const int blk = blockIdx.x;
  const int c = blk & 15, h = (blk >> 4) & 15, b = blk >> 8;
  const int tid = threadIdx.x;
  const int t0 = b*1024 + c*64;

  for (int i = tid; i < 2048; i += 256)
    Om[i>>5][i&31] = omega[i];
  for (int i = tid; i < 1024; i += 256){
    int j = i >> 4, m4 = (i & 15) << 2;
    size_t src = (size_t)(t0 + j)*1024 + h*64 + m4;
    float4 kv4 = *(const float4*)&Kraw[src];
    float4 xs4 = make_float4(kv4.x*0.35355339059327373f, kv4.y*0.35355339059327373f,
                             kv4.z*0.35355339059327373f, kv4.w*0.35355339059327373f);
    *(float4*)&Xs[j][m4] = xs4;
    *(float4*)&Vs[j][m4] = *(const float4*)&V[src];
  }
  __syncthreads();

  {
    const int tok = tid >> 2, q = tid & 3;
    float u[8] = {0,0,0,0,0,0,0,0};
    float hh = 0.f;
    for (int d = 0; d < 64; ++d){
      float xv = Xs[tok][d];
      hh = fmaf(xv, xv, hh);
      float4 o0 = *(const float4*)&Om[d][q*8];
      float4 o1 = *(const float4*)&Om[d][q*8+4];
      u[0]=fmaf(xv,o0.x,u[0]); u[1]=fmaf(xv,o0.y,u[1]);
      u[2]=fmaf(xv,o0.z,u[2]); u[3]=fmaf(xv,o0.w,u[3]);
      u[4]=fmaf(xv,o1.x,u[4]); u[5]=fmaf(xv,o1.y,u[5]);
      u[6]=fmaf(xv,o1.z,u[6]); u[7]=fmaf(xv,o1.w,u[7]);
    }
    hh *= 0.5f;
#pragma unroll
    for (int i = 0; i < 8; ++i){
      Ph[tok][q*8+i]    = expf( u[i] - hh) * 0.125f;
      Ph[tok][32+q*8+i] = expf(-u[i] - hh) * 0.125f;
    }
  }
  __syncthreads();

  {
    const int r = tid >> 2, c4 = (tid & 3) << 4;
    u16 tmp[16];
#pragma unroll
    for (int j = 0; j < 16; ++j) tmp[j] = f2bf(Ph[r][c4 + j]);
    size_t g = (size_t)(t0 + r)*1024 + h*64 + c4;
    *(uint4*)(Kb + g)     = *(uint4*)&tmp[0];
    *(uint4*)(Kb + g + 8) = *(uint4*)&tmp[8];
  }

  const int m = tid & 63, dg = tid >> 6;
  float acc[16] = {0.f};
  for (int j = 0; j < 64; ++j){
    float kv = Ph[j][m];
#pragma unroll
    for (int di = 0; di < 16; ++di)
      acc[di] = fmaf(Vs[j][dg*16+di], kv, acc[di]);
  }
  size_t outb = (size_t)blk * 4096;
#pragma unroll
  for (int di = 0; di < 16; ++di)
    KV[outb + (size_t)(dg*16+di)*64 + m] = acc[di];
  if (tid < 64){
    float s = 0.f;
    for (int j = 0; j < 64; ++j) s += Ph[j][tid];
    Ksum[(size_t)blk*64 + tid] = s;
  }
}

// ---------- exclusive prefix over chunks (elementwise; layout-agnostic) ----------
__global__ __launch_bounds__(256) void chunk_scan(float* __restrict__ KV, float* __restrict__ Ksum)
{
  int blk = blockIdx.x;
  int bh = blk >> 4, ec = blk & 15;
  int e = ec*256 + threadIdx.x;
  size_t base = (size_t)bh * 65536 + e;
  float run = 0.f;
  for (int c = 0; c < 16; ++c){
    size_t idx = base + (size_t)c*4096;
    float t = KV[idx]; KV[idx] = run; run += t;
  }
  if (ec == 0 && threadIdx.x < 64){
    size_t kb = (size_t)bh * 1024 + threadIdx.x;
    float rz = 0.f;
    for (int c = 0; c < 16; ++c){
      size_t idx = kb + c*64;
      float t = Ksum[idx]; Ksum[idx] = rz; rz += t;
    }
  }
}

// ---------- MFMA intra-chunk causal attention, FUSED favor(Q) ----------
__global__ __launch_bounds__(256) void attn_kernel(
    const float* __restrict__ Qraw, const u16* __restrict__ Kbf,
    const float* __restrict__ V, const float* __restrict__ KVt,
    const float* __restrict__ Ksum, const float* __restrict__ omega,
    u16* __restrict__ Outbf)
{
  __shared__ u16 Qs[64][72];
  __shared__ u16 Ks[64][72];
  __shared__ u16 Ss[64][72];
  __shared__ u16 Vt[64][72];
  __shared__ u16 Pt[64][72];
  __shared__ float Vrow[64][68];
  __shared__ float Om[64][32];
  __shared__ float densum[64];

  const int blk = blockIdx.x;
  const int c = blk & 15, h = (blk >> 4) & 15, b = blk >> 8;
  const int tid = threadIdx.x;
  const int lane = tid & 63, w = tid >> 6;
  const int quad = lane >> 4, l16 = lane & 15;
  const int t0 = b*1024 + c*64;
  const int r = tid >> 2, q4 = (tid & 3) << 4;
  const size_t g = (size_t)(t0 + r)*1024 + h*64 + q4;

  for (int i = tid; i < 2048; i += 256)
    Om[i>>5][i&31] = omega[i];
  {
    *(uint4*)&Ks[r][q4]   = *(const uint4*)(Kbf + g);
    *(uint4*)&Ks[r][q4+8] = *(const uint4*)(Kbf + g + 8);
    const float* vg = V + g;
    *(float4*)&Vrow[r][q4+0]  = *(const float4*)(vg+0);
    *(float4*)&Vrow[r][q4+4]  = *(const float4*)(vg+4);
    *(float4*)&Vrow[r][q4+8]  = *(const float4*)(vg+8);
    *(float4*)&Vrow[r][q4+12] = *(const float4*)(vg+12);
    const float* pg = KVt + (size_t)blk*4096 + r*64 + q4;
    u16 tmp[16];
#pragma unroll
    for (int j = 0; j < 16; ++j) tmp[j] = f2bf(pg[j]);
    *(uint4*)&Pt[r][q4]   = *(uint4*)&tmp[0];
    *(uint4*)&Pt[r][q4+8] = *(uint4*)&tmp[8];
  }
  __syncthreads();
  {
    const int d = tid >> 2, j16 = (tid & 3) << 4;
    u16 tmp[16];
#pragma unroll
    for (int j = 0; j < 16; ++j) tmp[j] = f2bf(Vrow[j16+j][d]);
    *(uint4*)&Vt[d][j16]   = *(uint4*)&tmp[0];
    *(uint4*)&Vt[d][j16+8] = *(uint4*)&tmp[8];
  }
  __syncthreads();
  {
    const float* qg = Qraw + g;
    float4 a0 = *(const float4*)(qg+0), a1 = *(const float4*)(qg+4);
    float4 a2 = *(const float4*)(qg+8), a3 = *(const float4*)(qg+12);
    const float sc = 0.35355339059327373f;
    *(float4*)&Vrow[r][q4+0]  = make_float4(a0.x*sc, a0.y*sc, a0.z*sc, a0.w*sc);
    *(float4*)&Vrow[r][q4+4]  = make_float4(a1.x*sc, a1.y*sc, a1.z*sc, a1.w*sc);
    *(float4*)&Vrow[r][q4+8]  = make_float4(a2.x*sc, a2.y*sc, a2.z*sc, a2.w*sc);
    *(float4*)&Vrow[r][q4+12] = make_float4(a3.x*sc, a3.y*sc, a3.z*sc, a3.w*sc);
  }
  __syncthreads();
  {
    const int tok = tid >> 2, q = tid & 3;
    float u[8] = {0,0,0,0,0,0,0,0};
    float hh = 0.f;
    for (int d = 0; d < 64; ++d){
      float xv = Vrow[tok][d];
      hh = fmaf(xv, xv, hh);
      float4 o0 = *(const float4*)&Om[d][q*8];
      float4 o1 = *(const float4*)&Om[d][q*8+4];
      u[0]=fmaf(xv,o0.x,u[0]); u[1]=fmaf(xv,o0.y,u[1]);
      u[2]=fmaf(xv,o0.z,u[2]); u[3]=fmaf(xv,o0.w,u[3]);
      u[4]=fmaf(xv,o1.x,u[4]); u[5]=fmaf(xv,o1.y,u[5]);
      u[6]=fmaf(xv,o1.z,u[6]); u[7]=fmaf(xv,o1.w,u[7]);
    }
    hh *= 0.5f;
#pragma unroll
    for (int i = 0; i < 8; i += 2){
      float e0 = expf( u[i]   - hh) * 0.125f;
      float e1 = expf( u[i+1] - hh) * 0.125f;
      *(u32*)&Qs[tok][q*8+i]    = (u32)f2bf(e0) | ((u32)f2bf(e1) << 16);
      float f0 = expf(-u[i]   - hh) * 0.125f;
      float f1 = expf(-u[i+1] - hh) * 0.125f;
      *(u32*)&Qs[tok][32+q*8+i] = (u32)f2bf(f0) | ((u32)f2bf(f1) << 16);
    }
  }
  __syncthreads();

  const int iw0 = w*16;
  bf16x8 aq0 = ldfrag(&Qs[iw0+l16][quad*8]);
  bf16x8 aq1 = ldfrag(&Qs[iw0+l16][32+quad*8]);
  fx4 sacc[4];
#pragma unroll
  for (int u = 0; u < 4; ++u){
    sacc[u] = (fx4){0.f,0.f,0.f,0.f};
    bf16x8 b0 = ldfrag(&Ks[u*16+l16][quad*8]);
    bf16x8 b1 = ldfrag(&Ks[u*16+l16][32+quad*8]);
    sacc[u] = __builtin_amdgcn_mfma_f32_16x16x32_bf16(aq0, b0, sacc[u], 0, 0, 0);
    sacc[u] = __builtin_amdgcn_mfma_f32_16x16x32_bf16(aq1, b1, sacc[u], 0, 0, 0);
  }
  float rs[4] = {0.f,0.f,0.f,0.f};
#pragma unroll
  for (int u = 0; u < 4; ++u){
    const int jl = u*16 + l16;
#pragma unroll
    for (int rr = 0; rr < 4; ++rr){
      const int il = iw0 + quad*4 + rr;
      float v = (jl <= il) ? sacc[u][rr] : 0.f;
      rs[rr] += v;
      Ss[il][jl] = f2bf(v);
    }
  }
#pragma unroll
  for (int off = 1; off < 16; off <<= 1){
#pragma unroll
    for (int rr = 0; rr < 4; ++rr) rs[rr] += __shfl_xor(rs[rr], off);
  }
  if (l16 == 0){
#pragma unroll
    for (int rr = 0; rr < 4; ++rr) densum[iw0 + quad*4 + rr] = rs[rr];
  }
  __syncthreads();

  {
    const int row = iw0 + l16;
    const float* zp = Ksum + (size_t)blk*64;
    float dp = 0.f;
#pragma unroll
    for (int m = 0; m < 16; ++m){
      const int mm = quad*16 + m;
      dp = fmaf(bf2f(Qs[row][mm]), zp[mm], dp);
    }
    dp += __shfl_xor(dp, 16);
    dp += __shfl_xor(dp, 32);
    if (quad == 0) densum[row] = densum[row] + dp + ATTN_EPS;
  }
  __syncthreads();

  bf16x8 as0 = ldfrag(&Ss[iw0+l16][quad*8]);
  bf16x8 as1 = ldfrag(&Ss[iw0+l16][32+quad*8]);
  fx4 oacc[4];
#pragma unroll
  for (int u = 0; u < 4; ++u){
    const int d0 = u*16;
    oacc[u] = (fx4){0.f,0.f,0.f,0.f};
    oacc[u] = __builtin_amdgcn_mfma_f32_16x16x32_bf16(as0, ldfrag(&Vt[d0+l16][quad*8]),    oacc[u], 0,0,0);
    oacc[u] = __builtin_amdgcn_mfma_f32_16x16x32_bf16(as1, ldfrag(&Vt[d0+l16][32+quad*8]), oacc[u], 0,0,0);
    oacc[u] = __builtin_amdgcn_mfma_f32_16x16x32_bf16(aq0, ldfrag(&Pt[d0+l16][quad*8]),    oacc[u], 0,0,0);
    oacc[u] = __builtin_amdgcn_mfma_f32_16x16x32_bf16(aq1, ldfrag(&Pt[d0+l16][32+quad*8]), oacc[u], 0,0,0);
  }
#pragma unroll
  for (int u = 0; u < 4; ++u){
    const int d = u*16 + l16;
#pragma unroll
    for (int rr = 0; rr < 4; ++rr){
      const int il = iw0 + quad*4 + rr;
      const float o = oacc[u][rr] / densum[il];
      Outbf[(size_t)(t0 + il)*1024 + h*64 + d] = f2bf(o);
    }
  }
}

// ---------- residual + LayerNorm: ln(X + Y0 + Y1 [+ Y2 + Y3]) ----------
__global__ __launch_bounds__(256) void resid_ln(
    const float* __restrict__ X, const float* __restrict__ Y0, const float* __restrict__ Y1,
    const float* __restrict__ Y2, const float* __restrict__ Y3,
    const float* __restrict__ g, const float* __restrict__ b,
    float* __restrict__ Dst, u16* __restrict__ DstBf,
    void* __restrict__ OutPtr, const int* __restrict__ flagp)
{
  __shared__ float rs[4], rss[4];
  int row = blockIdx.x, tid = threadIdx.x;
  int lane = tid & 63, wv = tid >> 6;
  size_t base = (size_t)row * 1024;
  int c = tid << 2;
  float4 xv = *(const float4*)&X[base + c];
  float4 y0 = *(const float4*)&Y0[base + c];
  float4 y1 = *(const float4*)&Y1[base + c];
  float v0 = xv.x+y0.x+y1.x, v1 = xv.y+y0.y+y1.y, v2 = xv.z+y0.z+y1.z, v3 = xv.w+y0.w+y1.w;
  if (Y2){
    float4 y2 = *(const float4*)&Y2[base + c];
    float4 y3 = *(const float4*)&Y3[base + c];
    v0 += y2.x + y3.x; v1 += y2.y + y3.y; v2 += y2.z + y3.z; v3 += y2.w + y3.w;
  }
  float s = v0+v1+v2+v3;
  float ss = v0*v0+v1*v1+v2*v2+v3*v3;
  for (int off = 32; off; off >>= 1){
    s  += __shfl_down(s, off);
    ss += __shfl_down(ss, off);
  }
  if (lane == 0){ rs[wv] = s; rss[wv] = ss; }
  __syncthreads();
  float S  = rs[0]+rs[1]+rs[2]+rs[3];
  float SS = rss[0]+rss[1]+rss[2]+rss[3];
  float mu = S * (1.f/1024.f);
  float var = SS * (1.f/1024.f) - mu*mu;
  float rinv = rsqrtf(var + LN_EPS);
  float4 gv = *(const float4*)(g + c);
  float4 bb = *(const float4*)(b + c);
  float o0 = (v0-mu)*rinv*gv.x + bb.x;
  float o1 = (v1-mu)*rinv*gv.y + bb.y;
  float o2 = (v2-mu)*rinv*gv.z + bb.z;
  float o3 = (v3-mu)*rinv*gv.w + bb.w;
  *(float4*)&Dst[base + c] = make_float4(o0,o1,o2,o3);
  uint2 ob;
  ob.x = (u32)f2bf(o0) | ((u32)f2bf(o1) << 16);
  ob.y = (u32)f2bf(o2) | ((u32)f2bf(o3) << 16);
  *(uint2*)(DstBf + base + c) = ob;
  if (OutPtr){
    if (*flagp){
      *(uint2*)((u16*)OutPtr + base + c) = ob;
    } else {
      *(float4*)((float*)OutPtr + base + c) = make_float4(o0,o1,o2,o3);
    }
  }
}

extern "C" void kernel_launch(void* const* d_in, const int* in_sizes, int n_in,
                              void* d_out, int out_size, void* d_ws, size_t ws_size,
                              hipStream_t stream)
{
  (void)in_sizes; (void)n_in; (void)out_size; (void)ws_size;

  float* ws   = (float*)d_ws;
  float* R    = ws;                    // 2M f32: x residual / layer input
  float* P0   = R  + 2097152;          // 4x2M contiguous: QKV out, split-K partials
  float* P1   = P0 + 2097152;
  float* P2   = P1 + 2097152;          // v f32
  float* P3   = P2 + 2097152;
  float* KVb  = P3 + 2097152;          // 2M: chunk states, then h (post-LN1) f32
  float* Ks   = KVb + 2097152;         // 32K chunk z
  float* smallP = Ks + 32768;          // 46080 f32 small params
  float* pend = smallP + 46080;
  int* flag = (int*)pend;
  u16* abf  = (u16*)(pend + 4);        // 2M: x / layer-out bf16
  u16* hbf  = abf  + 2097152;          // 2M: post-LN1 bf16
  u16* t1bf = hbf  + 2097152;          // 2M: attn out bf16
  u16* fbf  = t1bf + 2097152;          // 8M: ffn hidden bf16
  u16* kpbf = fbf  + 8388608;          // 2M: K-phi bf16
  u16* WtQ  = kpbf + 2097152;          // 12M: QKVO transposed, all layers
  u16* WtF1 = WtQ  + 12582912;         // 12M: FFN1 transposed, all layers
  u16* WtF2 = WtF1 + 12582912;         // 12M: FFN2 transposed, all layers

  float* bqF  = smallP + 0;
  float* boF  = smallP + 9216;
  float* omF  = smallP + 12288;
  float* l1gF = smallP + 18432;
  float* l1bF = smallP + 21504;
  float* l2gF = smallP + 24576;
  float* l2bF = smallP + 27648;
  float* bf1F = smallP + 30720;
  float* bf2F = smallP + 43008;

  detect_kernel<<<1, 64, 0, stream>>>((const u16*)d_in[10], flag);
  cvt_small<<<180, 256, 0, stream>>>(d_in[2], d_in[4], d_in[6], d_in[8], d_in[9],
                                     d_in[10], d_in[11], d_in[12], d_in[13],
                                     d_in[15], d_in[17], smallP, flag);
  cvt_x<<<8192, 256, 0, stream>>>(d_in[0], R, abf, 2097152, flag);

  transpose_cvtQ<<<dim3(32, 32, 12), 256, 0, stream>>>(d_in[1], d_in[3], d_in[5], d_in[7],
                                                       WtQ, flag);
  transpose_cvtL<<<dim3(128, 32, 3), 256, 0, stream>>>(d_in[14], WtF1, 1024, 4096,
                                                       4194304, 4194304, flag);
  transpose_cvtL<<<dim3(32, 128, 3), 256, 0, stream>>>(d_in[16], WtF2, 4096, 1024,
                                                       4194304, 4194304, flag);

  dim3 gQKV(8, 8, 3);     // 192 blocks (256x128 tiles)
  dim3 gO(8, 8, 4);       // 256 blocks, split-K z=4 (fills all CUs)
  dim3 gF1(32, 8, 1);     // 256 blocks
  dim3 gF2(8, 8, 4);      // 256 blocks, split-K z=4

  for (int l = 0; l < 3; ++l){
    const size_t wQ = (size_t)l * 4194304;

    mfma_gemm8<<<gQKV, 512, 0, stream>>>(abf, WtQ + wQ, bqF + l*1024, P0, (u16*)nullptr,
                                         1024, 1024, 0, 1024,
                                         1048576, 2097152, 3072, 1, 0);
    chunk_kv_favor<<<512, 256, 0, stream>>>(P1, P2, omF + l*2048, KVb, Ks, kpbf);
    chunk_scan<<<512, 256, 0, stream>>>(KVb, Ks);
    attn_kernel<<<512, 256, 0, stream>>>(P0, kpbf, P2, KVb, Ks, omF + l*2048, t1bf);

    mfma_gemm8<<<gO, 512, 0, stream>>>(t1bf, WtQ + wQ + 3145728, boF + l*1024, P0, (u16*)nullptr,
                                       1024, 1024, 256, 256,
                                       0, 2097152, 0, 0, 0);
    resid_ln<<<2048, 256, 0, stream>>>(R, P0, P1, P2, P3,
                                       l1gF + l*1024, l1bF + l*1024,
                                       KVb, hbf, nullptr, flag);

    mfma_gemm8<<<gF1, 512, 0, stream>>>(hbf, WtF1 + wQ, bf1F + l*4096, (float*)nullptr, fbf,
                                        4096, 1024, 0, 1024,
                                        0, 0, 0, 1, 1);

    mfma_gemm8<<<gF2, 512, 0, stream>>>(fbf, WtF2 + wQ, bf2F + l*1024, P0, (u16*)nullptr,
                                        1024, 4096, 1024, 1024,
                                        0, 2097152, 0, 0, 0);

    resid_ln<<<2048, 256, 0, stream>>>(KVb, P0, P1, P2, P3,
                                       l2gF + l*1024, l2bF + l*1024,
                                       R, abf, (l == 2) ? d_out : nullptr, flag);
  }
}